// Round 10
// baseline (1061.258 us; speedup 1.0000x reference)
//
#include <hip/hip_runtime.h>
#include <hip/hip_bf16.h>

#define NN 100000
#define NEDGE 1600000
#define NV (NN*32)
#define NEG 0.01f
#define EPS 1e-5f
#define NBLK 391            // ceil(NN/256)
#define NBKT 391            // node buckets (256 nodes each)
#define CHUNK 4096          // edges per binning block
#define NCBLK 391           // ceil(NEDGE/CHUNK)
#define DCAP 6144           // LDS stage capacity in k_csr (mean 4096 + 32 sigma)
#define STC 64              // stat copies (contention spread)
#define ST_STRIDE 4096      // STC * 64
#define NGBLK 1563          // ceil(NN/64) for fused gather+upd
#define NTILE 3125          // NN/32 tiles for k_nl
#define PLANE_SH (NN*16)    // plane stride in shorts (3.2 MB per plane)

// ---- static device arena (fp32) ----
#define OFF_STATS 0
#define STATS_F  (22*ST_STRIDE)
#define OFF_PA   STATS_F
#define OFF_PB   (OFF_PA + NV)
#define OFF_TACT (OFF_PB + NV)           // post-act bf16 msgs, TWO 3.2MB feature planes
#define OFF_MSGB (OFF_TACT + NV)         // pre-act bf16 msgs
#define OFF_RING (OFF_MSGB + NV/2)
#define OFF_WF   (OFF_RING + 4*NV)       // bf16 weight frags for final MLP (51200 shorts)
#define ARENA_F  (OFF_WF + 25600)

// weight-frag section bases in uint4 (16B) units
#define W0B 0
#define W1B 1024
#define W2B 5120
#define W3B 6144

__device__ __align__(16) float gA[ARENA_F];
__device__ int g_rowptr[NN + 1];
__device__ int g_csr[NEDGE];
__device__ int g_bin[NEDGE];       // bucket-grouped packed edges: (src<<8)|dlocal
__device__ int g_bcnt[NBKT];
__device__ int g_boff[NBKT];
__device__ int g_btail[NBKT];

__device__ __forceinline__ float lrelu(float v) { return v > 0.f ? v : v * NEG; }
__device__ __forceinline__ unsigned short f2b(float v) {
    __hip_bfloat16 b = __float2bfloat16(v);
    return *reinterpret_cast<unsigned short*>(&b);
}
__device__ __forceinline__ float b2f(unsigned short u) {
    __hip_bfloat16 b = *reinterpret_cast<__hip_bfloat16*>(&u);
    return __bfloat162float(b);
}

// ---------------- zero stats + bucket counts ----------------
__global__ void k_zero_v19()
{
    int i = blockIdx.x * 256 + threadIdx.x;
    if (i < STATS_F) gA[i] = 0.f;
    if (i < NBKT) g_bcnt[i] = 0;
}

// ---------------- bucket histogram (LDS-staged, low-contention) ----------------
__global__ __launch_bounds__(256) void k_bcnt_v19(const int* __restrict__ col)
{
    __shared__ int hist[NBKT];
    int tid = threadIdx.x;
    for (int b = tid; b < NBKT; b += 256) hist[b] = 0;
    __syncthreads();
    int e0 = blockIdx.x * CHUNK;
    #pragma unroll
    for (int r = 0; r < CHUNK / 256; ++r) {
        int e = e0 + r * 256 + tid;
        if (e < NEDGE) atomicAdd(&hist[col[NEDGE + e] >> 8], 1);
    }
    __syncthreads();
    for (int b = tid; b < NBKT; b += 256) {
        int v = hist[b];
        if (v) atomicAdd(&g_bcnt[b], v);
    }
}

// ---------------- scan bucket counts -> offsets + tails ----------------
__global__ __launch_bounds__(512) void k_bscan_v19()
{
    __shared__ int s[512];
    int t = threadIdx.x;
    int v = (t < NBKT) ? g_bcnt[t] : 0;
    s[t] = v;
    __syncthreads();
    for (int off = 1; off < 512; off <<= 1) {
        int u = (t >= off) ? s[t - off] : 0;
        __syncthreads();
        s[t] += u;
        __syncthreads();
    }
    if (t < NBKT) {
        int o = s[t] - v;
        g_boff[t] = o;
        g_btail[t] = o;
    }
}

// ---------------- bin edges into bucket-contiguous regions (chunked append) ----------------
__global__ __launch_bounds__(256) void k_binfill_v19(const int* __restrict__ col)
{
    __shared__ int ssrc[CHUNK];
    __shared__ int sdst[CHUNK];
    __shared__ int hist[NBKT];
    __shared__ int boffL[NBKT];
    __shared__ int cnt2[NBKT];
    int tid = threadIdx.x;
    for (int b = tid; b < NBKT; b += 256) { hist[b] = 0; cnt2[b] = 0; }
    __syncthreads();
    int e0 = blockIdx.x * CHUNK;
    #pragma unroll
    for (int r = 0; r < CHUNK / 256; ++r) {
        int i = r * 256 + tid;
        int e = e0 + i;
        if (e < NEDGE) {
            int s = col[e];
            int d = col[NEDGE + e];
            ssrc[i] = s;
            sdst[i] = d;
            atomicAdd(&hist[d >> 8], 1);
        }
    }
    __syncthreads();
    for (int b = tid; b < NBKT; b += 256) {
        int h = hist[b];
        if (h) boffL[b] = atomicAdd(&g_btail[b], h);
    }
    __syncthreads();
    #pragma unroll
    for (int r = 0; r < CHUNK / 256; ++r) {
        int i = r * 256 + tid;
        int e = e0 + i;
        if (e < NEDGE) {
            int d = sdst[i];
            int b = d >> 8;
            int rk = atomicAdd(&cnt2[b], 1);
            g_bin[boffL[b] + rk] = (ssrc[i] << 8) | (d & 255);
        }
    }
}

// ------- per-bucket counting scatter -> CSR grouped by (node, src-segment) -------
__global__ __launch_bounds__(256) void k_csr_v24()
{
    __shared__ int stg[DCAP];
    __shared__ int c1[1024];     // [dlocal][seg] counts
    __shared__ int sgb[1024];    // [dlocal][seg] start within row
    __shared__ int c2[1024];     // scatter ranks
    __shared__ int sc[256];
    __shared__ int sl[256];
    int tid = threadIdx.x, b = blockIdx.x;
    int base = g_boff[b];
    int cntE = g_bcnt[b];
    #pragma unroll
    for (int k = 0; k < 4; ++k) { c1[tid + 256 * k] = 0; c2[tid + 256 * k] = 0; }
    __syncthreads();
    for (int i = tid; i < cntE; i += 256) {
        int p = g_bin[base + i];
        if (i < DCAP) stg[i] = p;
        atomicAdd(&c1[((p & 255) << 2) | (p >> 23)], 1);
    }
    __syncthreads();
    int t0 = c1[tid * 4], t1 = c1[tid * 4 + 1], t2 = c1[tid * 4 + 2], t3 = c1[tid * 4 + 3];
    int deg = t0 + t1 + t2 + t3;
    sgb[tid * 4]     = 0;
    sgb[tid * 4 + 1] = t0;
    sgb[tid * 4 + 2] = t0 + t1;
    sgb[tid * 4 + 3] = t0 + t1 + t2;
    sc[tid] = deg;
    __syncthreads();
    for (int off = 1; off < 256; off <<= 1) {
        int u = (tid >= off) ? sc[tid - off] : 0;
        __syncthreads();
        sc[tid] += u;
        __syncthreads();
    }
    int loff = sc[tid] - deg;
    sl[tid] = loff;
    int node = b * 256 + tid;
    if (node < NN) g_rowptr[node] = base + loff;
    if (b == NBKT - 1 && tid == 0) g_rowptr[NN] = NEDGE;
    __syncthreads();
    for (int i = tid; i < cntE; i += 256) {
        int p = (i < DCAP) ? stg[i] : g_bin[base + i];
        int dl = p & 255;
        int k2 = (dl << 2) | (p >> 23);
        int rk = atomicAdd(&c2[k2], 1);
        g_csr[base + sl[dl] + sgb[k2] + rk] = p >> 8;
    }
}

// ---------------- init layer 0: PA = x*Wi0 + bi0, stats ----------------
__global__ void k_init0_v17(const float* __restrict__ x, const float* __restrict__ Wi0,
                            const float* __restrict__ bi0)
{
    int j = threadIdx.x & 31, ns = threadIdx.x >> 5;
    float w = Wi0[j];
    float bb = bi0[j];
    __shared__ float red[64];
    if (threadIdx.x < 64) red[threadIdx.x] = 0.f;
    __syncthreads();
    float s1 = 0.f, s2 = 0.f;
    for (int t = blockIdx.x; t < NN / 8; t += gridDim.x) {
        int n = t * 8 + ns;
        float v = x[n] * w + bb;
        gA[OFF_PA + n * 32 + j] = v;
        s1 += v; s2 += v * v;
    }
    atomicAdd(&red[j], s1);
    atomicAdd(&red[j + 32], s2);
    __syncthreads();
    if (threadIdx.x < 64)
        atomicAdd(&gA[OFF_STATS + (blockIdx.x & (STC - 1)) * 64 + threadIdx.x], red[threadIdx.x]);
}

// ------- BN+LReLU (+resid) (+feats) (+fused 32x32 linear + stats), 32-node tiles -------
__global__ __launch_bounds__(256) void k_nl_v24(int off_in, int off_out, int out_msg, int st_in,
                         const float* __restrict__ gamma, const float* __restrict__ beta,
                         int off_resid, int off_feats,
                         const float* __restrict__ Wn, const float* __restrict__ bn,
                         int st_out)
{
    int tid = threadIdx.x;
    int j = tid & 31, grp = tid >> 5;
    __shared__ float sstat[64];
    __shared__ float red[64];
    __shared__ float sH[32][32];
    if (tid < 64) {
        red[tid] = 0.f;
        float acc = 0.f;
        int base = st_in + tid;
        #pragma unroll 8
        for (int c = 0; c < STC; ++c) acc += gA[base + c * 64];
        sstat[tid] = acc;
    }
    __syncthreads();
    float mean = sstat[j] * (1.f / NN);
    float var  = sstat[32 + j] * (1.f / NN) - mean * mean;
    float scale = gamma[j] * rsqrtf(var + EPS);
    float shift = beta[j] - mean * scale;

    float wc[32]; float bb = 0.f;
    if (Wn) {
        #pragma unroll
        for (int k = 0; k < 32; ++k) wc[k] = Wn[k * 32 + j];
        bb = bn[j];
    }
    unsigned short* mb = (unsigned short*)(gA + OFF_MSGB);
    float s1 = 0.f, s2 = 0.f;
    for (int t = blockIdx.x; t < NTILE; t += gridDim.x) {
        int base = t * 1024;
        #pragma unroll
        for (int k = 0; k < 4; ++k) {
            int idx = tid + 256 * k;
            float v = gA[off_in + base + idx];
            v = lrelu(scale * v + shift);
            if (off_resid >= 0) v += gA[off_resid + base + idx];
            if (off_feats >= 0) gA[off_feats + base + idx] = v;
            ((float*)sH)[idx] = v;
        }
        if (Wn) {
            __syncthreads();
            #pragma unroll
            for (int q = 0; q < 4; ++q) {
                int nl = grp * 4 + q;
                float acc = bb;
                #pragma unroll
                for (int k = 0; k < 32; k += 4) {
                    float4 h4 = *(const float4*)&sH[nl][k];
                    acc += h4.x * wc[k] + h4.y * wc[k + 1] + h4.z * wc[k + 2] + h4.w * wc[k + 3];
                }
                int n = t * 32 + nl;
                if (out_msg) mb[n * 32 + j] = f2b(acc);
                else gA[off_out + n * 32 + j] = acc;
                s1 += acc; s2 += acc * acc;
            }
            __syncthreads();
        }
    }
    if (Wn) {
        atomicAdd(&red[j], s1);
        atomicAdd(&red[j + 32], s2);
        __syncthreads();
        if (tid < 64)
            atomicAdd(&gA[st_out + (blockIdx.x & (STC - 1)) * 64 + tid], red[tid]);
    }
}

// ---- per-node post-activation into TWO 3.2MB feature planes (each fits per-XCD L2) ----
// plane 0: feats 0-15, plane 1: feats 16-31; plane layout [node][16] bf16.
__global__ __launch_bounds__(256) void k_act_v25(int st_msg,
                                                 const float* __restrict__ gm,
                                                 const float* __restrict__ bem)
{
    __shared__ float sstat[64];
    __shared__ float scl[32], shf[32];
    int tid = threadIdx.x;
    if (tid < 64) {
        float acc = 0.f;
        int base = st_msg + tid;
        #pragma unroll 8
        for (int c = 0; c < STC; ++c) acc += gA[base + c * 64];
        sstat[tid] = acc;
    }
    __syncthreads();
    if (tid < 32) {
        float mean = sstat[tid] * (1.f / NN);
        float var  = sstat[32 + tid] * (1.f / NN) - mean * mean;
        float s = gm[tid] * rsqrtf(var + EPS);
        scl[tid] = s;
        shf[tid] = bem[tid] - mean * s;
    }
    __syncthreads();
    int idx = blockIdx.x * 256 + tid;          // uint4 index over NV/8 of MSGB
    if (idx >= NV / 8) return;
    const uint4* src = (const uint4*)(gA + OFF_MSGB);
    uint4* dst = (uint4*)(gA + OFF_TACT);
    uint4 m = src[idx];
    int q = idx & 3;                  // quad within node (8 feats each)
    int node = idx >> 2;
    int fb = q * 8;
    uint4 o;
    #pragma unroll
    for (int w = 0; w < 4; ++w) {
        unsigned int u = (&m.x)[w];
        int f0 = fb + 2 * w;
        float vlo = lrelu(scl[f0]     * __uint_as_float(u << 16)         + shf[f0]);
        float vhi = lrelu(scl[f0 + 1] * __uint_as_float(u & 0xffff0000u) + shf[f0 + 1]);
        (&o.x)[w] = (unsigned int)f2b(vlo) | ((unsigned int)f2b(vhi) << 16);
    }
    // q<2 -> plane0 uint4 (node*2 + q); q>=2 -> plane1 uint4 (node*2 + q-2)
    int di = node * 2 + (q & 1) + ((q >> 1) ? (NN * 2) : 0);
    dst[di] = o;
}

// ======== fused gather (2-pass over L2-resident feature planes) + update GEMM ========
// Pass p reads only plane p (3.2MB, fits 4MB per-XCD L2): 4 lanes/node x 8B uint2
// per edge, 4-edge unroll, quad-shuffled CSR, no barriers. Summation order per
// feature identical to v24 (ascending e) -> bitwise-identical numerics.
__global__ __launch_bounds__(256) void k_gupd_v25(int off_h,
                                                  const float* __restrict__ Wu_i,
                                                  const float* __restrict__ bu_i,
                                                  int st_out)
{
    __shared__ float sH[64][36];
    __shared__ float sAgg[64][36];
    __shared__ float red[64];
    int tid = threadIdx.x;
    int nb = blockIdx.x * 64;

    if (tid < 64) red[tid] = 0.f;
    {
        const float* hp = gA + off_h + nb * 32;
        int lim = min(2048, (NN - nb) * 32);
        for (int idx = tid; idx < lim; idx += 256)
            sH[idx >> 5][idx & 31] = hp[idx];
    }

    // ---- phase A: 2-pass gather ----
    {
        int nl = tid >> 2;          // local node 0..63
        int g  = tid & 3;           // lane-in-quad: feats (p*16 + g*4 .. +4)
        int n  = nb + nl;
        float a[8];
        #pragma unroll
        for (int q = 0; q < 8; ++q) a[q] = 0.f;
        if (n < NN) {
            int e0 = g_rowptr[n], e1 = g_rowptr[n + 1];
            const unsigned short* tb0 = (const unsigned short*)(gA + OFF_TACT);
            #pragma unroll
            for (int p = 0; p < 2; ++p) {
                const unsigned short* tb = tb0 + p * PLANE_SH;
                float a0 = 0.f, a1 = 0.f, a2 = 0.f, a3 = 0.f;
                int e = e0;
                for (; e + 3 < e1; e += 4) {
                    int sg = g_csr[e + g];
                    int s0 = __shfl(sg, 0, 4);
                    int s1 = __shfl(sg, 1, 4);
                    int s2 = __shfl(sg, 2, 4);
                    int s3 = __shfl(sg, 3, 4);
                    uint2 m0 = *(const uint2*)(tb + (s0 << 4) + (g << 2));
                    uint2 m1 = *(const uint2*)(tb + (s1 << 4) + (g << 2));
                    uint2 m2 = *(const uint2*)(tb + (s2 << 4) + (g << 2));
                    uint2 m3 = *(const uint2*)(tb + (s3 << 4) + (g << 2));
                    a0 += __uint_as_float(m0.x << 16) + __uint_as_float(m1.x << 16)
                        + __uint_as_float(m2.x << 16) + __uint_as_float(m3.x << 16);
                    a1 += __uint_as_float(m0.x & 0xffff0000u) + __uint_as_float(m1.x & 0xffff0000u)
                        + __uint_as_float(m2.x & 0xffff0000u) + __uint_as_float(m3.x & 0xffff0000u);
                    a2 += __uint_as_float(m0.y << 16) + __uint_as_float(m1.y << 16)
                        + __uint_as_float(m2.y << 16) + __uint_as_float(m3.y << 16);
                    a3 += __uint_as_float(m0.y & 0xffff0000u) + __uint_as_float(m1.y & 0xffff0000u)
                        + __uint_as_float(m2.y & 0xffff0000u) + __uint_as_float(m3.y & 0xffff0000u);
                }
                for (; e < e1; ++e) {
                    int s0 = g_csr[e];
                    uint2 m0 = *(const uint2*)(tb + (s0 << 4) + (g << 2));
                    a0 += __uint_as_float(m0.x << 16);
                    a1 += __uint_as_float(m0.x & 0xffff0000u);
                    a2 += __uint_as_float(m0.y << 16);
                    a3 += __uint_as_float(m0.y & 0xffff0000u);
                }
                a[p * 4]     = a0;
                a[p * 4 + 1] = a1;
                a[p * 4 + 2] = a2;
                a[p * 4 + 3] = a3;
            }
        }
        // lane g holds feats (g*4..g*4+3) from pass0 and (16+g*4..) from pass1
        *(float4*)&sAgg[nl][g * 4]      = make_float4(a[0], a[1], a[2], a[3]);
        *(float4*)&sAgg[nl][16 + g * 4] = make_float4(a[4], a[5], a[6], a[7]);
    }
    __syncthreads();

    // ---- phase B: update GEMM ----
    {
        int j = tid & 31, ns = tid >> 5;
        float wc[64];
        #pragma unroll
        for (int k = 0; k < 64; ++k) wc[k] = Wu_i[k * 32 + j];
        float bb = bu_i[j];
        float s1 = 0.f, s2 = 0.f;
        #pragma unroll
        for (int it = 0; it < 8; ++it) {
            int nl = it * 8 + ns;
            int n = nb + nl;
            if (n >= NN) break;
            float acc = bb;
            #pragma unroll
            for (int k = 0; k < 32; k += 4) {
                float4 h4 = *(const float4*)&sH[nl][k];
                acc += h4.x * wc[k] + h4.y * wc[k + 1] + h4.z * wc[k + 2] + h4.w * wc[k + 3];
                float4 a4 = *(const float4*)&sAgg[nl][k];
                acc += a4.x * wc[32 + k] + a4.y * wc[32 + k + 1] + a4.z * wc[32 + k + 2] + a4.w * wc[32 + k + 3];
            }
            gA[OFF_PB + n * 32 + j] = acc;
            s1 += acc; s2 += acc * acc;
        }
        atomicAdd(&red[j], s1);
        atomicAdd(&red[j + 32], s2);
        __syncthreads();
        if (tid < 64)
            atomicAdd(&gA[st_out + (blockIdx.x & (STC - 1)) * 64 + tid], red[tid]);
    }
}

// ================= MFMA final MLP =================
typedef __attribute__((ext_vector_type(8))) short bf16x8;
typedef __attribute__((ext_vector_type(4))) float f32x4;

union FC { uint4 u; bf16x8 b; };

#define MFMA(a, b, c) __builtin_amdgcn_mfma_f32_16x16x32_bf16(a, b, c, 0, 0, 0)

__device__ __forceinline__ bf16x8 ld_wf(const uint4* p) {
    FC c; c.u = *p; return c.b;
}

__device__ __forceinline__ f32x4 ld_bias4(const float* p) {
    float4 t = *(const float4*)p;
    f32x4 r; r[0] = t.x; r[1] = t.y; r[2] = t.z; r[3] = t.w; return r;
}

__device__ __forceinline__ f32x4 lrelu4(f32x4 v) {
    f32x4 r;
    #pragma unroll
    for (int k = 0; k < 4; ++k) r[k] = v[k] > 0.f ? v[k] : v[k] * NEG;
    return r;
}

__device__ __forceinline__ void splitpack(const float* v, bf16x8& hi, bf16x8& lo) {
    unsigned int h[4], l[4];
    #pragma unroll
    for (int k = 0; k < 4; ++k) {
        unsigned short h0 = f2b(v[2*k]), h1 = f2b(v[2*k+1]);
        float r0 = v[2*k]   - b2f(h0);
        float r1 = v[2*k+1] - b2f(h1);
        h[k] = (unsigned int)h0 | ((unsigned int)h1 << 16);
        l[k] = (unsigned int)f2b(r0) | ((unsigned int)f2b(r1) << 16);
    }
    FC ch; ch.u = make_uint4(h[0], h[1], h[2], h[3]); hi = ch.b;
    FC cl; cl.u = make_uint4(l[0], l[1], l[2], l[3]); lo = cl.b;
}

__global__ __launch_bounds__(256) void k_wprep_v18(const float* __restrict__ W0,
                                                   const float* __restrict__ W1,
                                                   const float* __restrict__ W2,
                                                   const float* __restrict__ W3)
{
    int i = blockIdx.x * 256 + threadIdx.x;
    if (i >= 51200) return;
    const float* src; int Nout, nk; int r = i;
    if (r < 8192)       { src = W0; Nout = 256; nk = 1; }
    else if (r < 40960) { src = W1; Nout = 128; nk = 8; r -= 8192; }
    else if (r < 49152) { src = W2; Nout = 64;  nk = 4; r -= 40960; }
    else                { src = W3; Nout = 32;  nk = 2; r -= 49152; }
    int frag = r >> 9;
    int lane = (r >> 3) & 63;
    int j = r & 7;
    int T = frag / nk, s = frag - T * nk;
    int g = lane >> 4;
    int outf = T * 16 + (lane & 15);
    int inf = 32 * s + 16 * (j >> 2) + 4 * g + (j & 3);
    unsigned short* dst = (unsigned short*)(gA + OFF_WF);
    dst[i] = f2b(src[inf * Nout + outf]);
}

__global__ __launch_bounds__(256) void k_final_v18(
    int off_h,
    const float* __restrict__ bf0, const float* __restrict__ bf1,
    const float* __restrict__ bf2, const float* __restrict__ bf3,
    const float* __restrict__ Wo,  const float* __restrict__ bo,
    float* __restrict__ out)
{
    int lane = threadIdx.x & 63;
    int wave = threadIdx.x >> 6;
    int c = lane & 15;
    int g = lane >> 4;
    int nb = blockIdx.x * 128 + wave * 32;
    int n0 = nb + c;
    int n1 = nb + 16 + c;
    int ld0 = min(n0, NN - 1), ld1 = min(n1, NN - 1);

    const float* h = gA + off_h;
    const uint4* WF = (const uint4*)(gA + OFF_WF);

    float4 ia0 = *(const float4*)&h[ld0 * 32 + 4 * g];
    float4 ib0 = *(const float4*)&h[ld0 * 32 + 16 + 4 * g];
    float4 ia1 = *(const float4*)&h[ld1 * 32 + 4 * g];
    float4 ib1 = *(const float4*)&h[ld1 * 32 + 16 + 4 * g];
    bf16x8 Bh0, Bl0, Bh1, Bl1;
    {
        float v0[8] = {ia0.x, ia0.y, ia0.z, ia0.w, ib0.x, ib0.y, ib0.z, ib0.w};
        float v1[8] = {ia1.x, ia1.y, ia1.z, ia1.w, ib1.x, ib1.y, ib1.z, ib1.w};
        splitpack(v0, Bh0, Bl0);
        splitpack(v1, Bh1, Bl1);
    }

    f32x4 A0[16][2];
    #pragma unroll
    for (int t = 0; t < 16; ++t) {
        f32x4 ci = ld_bias4(bf0 + t * 16 + 4 * g);
        bf16x8 w = ld_wf(WF + W0B + t * 64 + lane);
        f32x4 d0 = MFMA(w, Bh0, ci);
        d0 = MFMA(w, Bl0, d0);
        f32x4 d1 = MFMA(w, Bh1, ci);
        d1 = MFMA(w, Bl1, d1);
        A0[t][0] = lrelu4(d0);
        A0[t][1] = lrelu4(d1);
    }

    f32x4 A1[8][2];
    #pragma unroll
    for (int T = 0; T < 8; ++T) {
        f32x4 ci = ld_bias4(bf1 + T * 16 + 4 * g);
        A1[T][0] = ci; A1[T][1] = ci;
    }
    #pragma unroll
    for (int s = 0; s < 8; ++s) {
        bf16x8 bh[2], bl[2];
        #pragma unroll
        for (int u = 0; u < 2; ++u) {
            float vv[8] = {A0[2*s][u][0], A0[2*s][u][1], A0[2*s][u][2], A0[2*s][u][3],
                           A0[2*s+1][u][0], A0[2*s+1][u][1], A0[2*s+1][u][2], A0[2*s+1][u][3]};
            splitpack(vv, bh[u], bl[u]);
        }
        #pragma unroll
        for (int T = 0; T < 8; ++T) {
            bf16x8 w = ld_wf(WF + W1B + (T * 8 + s) * 64 + lane);
            A1[T][0] = MFMA(w, bh[0], A1[T][0]);
            A1[T][0] = MFMA(w, bl[0], A1[T][0]);
            A1[T][1] = MFMA(w, bh[1], A1[T][1]);
            A1[T][1] = MFMA(w, bl[1], A1[T][1]);
        }
    }
    #pragma unroll
    for (int T = 0; T < 8; ++T) { A1[T][0] = lrelu4(A1[T][0]); A1[T][1] = lrelu4(A1[T][1]); }

    f32x4 A2[4][2];
    #pragma unroll
    for (int T = 0; T < 4; ++T) {
        f32x4 ci = ld_bias4(bf2 + T * 16 + 4 * g);
        A2[T][0] = ci; A2[T][1] = ci;
    }
    #pragma unroll
    for (int s = 0; s < 4; ++s) {
        bf16x8 bh[2], bl[2];
        #pragma unroll
        for (int u = 0; u < 2; ++u) {
            float vv[8] = {A1[2*s][u][0], A1[2*s][u][1], A1[2*s][u][2], A1[2*s][u][3],
                           A1[2*s+1][u][0], A1[2*s+1][u][1], A1[2*s+1][u][2], A1[2*s+1][u][3]};
            splitpack(vv, bh[u], bl[u]);
        }
        #pragma unroll
        for (int T = 0; T < 4; ++T) {
            bf16x8 w = ld_wf(WF + W2B + (T * 4 + s) * 64 + lane);
            A2[T][0] = MFMA(w, bh[0], A2[T][0]);
            A2[T][0] = MFMA(w, bl[0], A2[T][0]);
            A2[T][1] = MFMA(w, bh[1], A2[T][1]);
            A2[T][1] = MFMA(w, bl[1], A2[T][1]);
        }
    }
    #pragma unroll
    for (int T = 0; T < 4; ++T) { A2[T][0] = lrelu4(A2[T][0]); A2[T][1] = lrelu4(A2[T][1]); }

    f32x4 A3[2][2];
    #pragma unroll
    for (int T = 0; T < 2; ++T) {
        f32x4 ci = ld_bias4(bf3 + T * 16 + 4 * g);
        A3[T][0] = ci; A3[T][1] = ci;
    }
    #pragma unroll
    for (int s = 0; s < 2; ++s) {
        bf16x8 bh[2], bl[2];
        #pragma unroll
        for (int u = 0; u < 2; ++u) {
            float vv[8] = {A2[2*s][u][0], A2[2*s][u][1], A2[2*s][u][2], A2[2*s][u][3],
                           A2[2*s+1][u][0], A2[2*s+1][u][1], A2[2*s+1][u][2], A2[2*s+1][u][3]};
            splitpack(vv, bh[u], bl[u]);
        }
        #pragma unroll
        for (int T = 0; T < 2; ++T) {
            bf16x8 w = ld_wf(WF + W3B + (T * 2 + s) * 64 + lane);
            A3[T][0] = MFMA(w, bh[0], A3[T][0]);
            A3[T][0] = MFMA(w, bl[0], A3[T][0]);
            A3[T][1] = MFMA(w, bh[1], A3[T][1]);
            A3[T][1] = MFMA(w, bl[1], A3[T][1]);
        }
    }
    #pragma unroll
    for (int T = 0; T < 2; ++T) { A3[T][0] = lrelu4(A3[T][0]); A3[T][1] = lrelu4(A3[T][1]); }

    float4 woa = *(const float4*)&Wo[4 * g];
    float4 wob = *(const float4*)&Wo[16 + 4 * g];
    float z0 = A3[0][0][0]*woa.x + A3[0][0][1]*woa.y + A3[0][0][2]*woa.z + A3[0][0][3]*woa.w
             + A3[1][0][0]*wob.x + A3[1][0][1]*wob.y + A3[1][0][2]*wob.z + A3[1][0][3]*wob.w;
    float z1 = A3[0][1][0]*woa.x + A3[0][1][1]*woa.y + A3[0][1][2]*woa.z + A3[0][1][3]*woa.w
             + A3[1][1][0]*wob.x + A3[1][1][1]*wob.y + A3[1][1][2]*wob.z + A3[1][1][3]*wob.w;
    z0 += __shfl_xor(z0, 16); z0 += __shfl_xor(z0, 32);
    z1 += __shfl_xor(z1, 16); z1 += __shfl_xor(z1, 32);
    float bb = bo[0];
    if (g == 0 && n0 < NN) out[n0] = 1.f / (1.f + __expf(-(z0 + bb)));
    if (g == 1 && n1 < NN) out[n1] = 1.f / (1.f + __expf(-(z1 + bb)));
}

extern "C" void kernel_launch(void* const* d_in, const int* in_sizes, int n_in,
                              void* d_out, int out_size, void* d_ws, size_t ws_size,
                              hipStream_t stream)
{
    (void)in_sizes; (void)n_in; (void)out_size; (void)d_ws; (void)ws_size;
    float* out = (float*)d_out;

    const float* x   = (const float*)d_in[0];
    const int*  col  = (const int*) d_in[1];
    const float* Wi0 = (const float*)d_in[2];
    const float* bi0 = (const float*)d_in[3];
    const float* gi0 = (const float*)d_in[4];
    const float* bei0= (const float*)d_in[5];
    const float* Wi1 = (const float*)d_in[6];
    const float* bi1 = (const float*)d_in[7];
    const float* gi1 = (const float*)d_in[8];
    const float* bei1= (const float*)d_in[9];
    const float* Wm  = (const float*)d_in[10];
    const float* bm  = (const float*)d_in[11];
    const float* gm  = (const float*)d_in[12];
    const float* bem = (const float*)d_in[13];
    const float* Wu  = (const float*)d_in[14];
    const float* bu  = (const float*)d_in[15];
    const float* gu  = (const float*)d_in[16];
    const float* beu = (const float*)d_in[17];
    const float* Wf0 = (const float*)d_in[18];
    const float* bf0 = (const float*)d_in[19];
    const float* Wf1 = (const float*)d_in[20];
    const float* bf1 = (const float*)d_in[21];
    const float* Wf2 = (const float*)d_in[22];
    const float* bf2 = (const float*)d_in[23];
    const float* Wf3 = (const float*)d_in[24];
    const float* bf3 = (const float*)d_in[25];
    const float* Wo  = (const float*)d_in[26];
    const float* bo  = (const float*)d_in[27];

    const int st_i0 = OFF_STATS;
    const int st_i1 = OFF_STATS + ST_STRIDE;
    const int st_m  = OFF_STATS + 2 * ST_STRIDE;    // + i*ST_STRIDE
    const int st_u  = OFF_STATS + 12 * ST_STRIDE;   // + i*ST_STRIDE

    const int RING[4] = { OFF_RING, OFF_RING + NV, OFF_RING + 2 * NV, OFF_RING + 3 * NV };

    dim3 blk(256);
    k_zero_v19<<<NBLK, blk, 0, stream>>>();
    k_bcnt_v19<<<NCBLK, blk, 0, stream>>>(col);
    k_bscan_v19<<<1, 512, 0, stream>>>();
    k_binfill_v19<<<NCBLK, blk, 0, stream>>>(col);
    k_csr_v24<<<NBKT, blk, 0, stream>>>();
    k_wprep_v18<<<200, blk, 0, stream>>>(Wf0, Wf1, Wf2, Wf3);

    // init MLP: x -> h0 (ring[0]); last k_nl chains layer-0 msg linear into bf16 MSGB
    k_init0_v17<<<1024, blk, 0, stream>>>(x, Wi0, bi0);
    k_nl_v24<<<782, blk, 0, stream>>>(OFF_PA, OFF_PB, 0, st_i0, gi0, bei0, -1, -1, Wi1, bi1, st_i1);
    k_nl_v24<<<782, blk, 0, stream>>>(OFF_PB, 0, 1, st_i1, gi1, bei1, -1, RING[0], Wm, bm, st_m);

    for (int i = 0; i < 10; ++i) {
        int h_cur = RING[i & 3];
        int h_new = RING[(i + 1) & 3];
        int resid = (i >= 2) ? RING[(i - 2) & 3] : -1;
        k_act_v25<<<1563, blk, 0, stream>>>(st_m + i * ST_STRIDE, gm + i * 32, bem + i * 32);
        k_gupd_v25<<<NGBLK, blk, 0, stream>>>(h_cur, Wu + i * 2048, bu + i * 32,
                                              st_u + i * ST_STRIDE);
        const float* Wn = (i < 9) ? (Wm + (i + 1) * 1024) : nullptr;
        const float* bn = (i < 9) ? (bm + (i + 1) * 32) : nullptr;
        int st_next = (i < 9) ? (st_m + (i + 1) * ST_STRIDE) : 0;
        k_nl_v24<<<782, blk, 0, stream>>>(OFF_PB, 0, 1, st_u + i * ST_STRIDE,
                                          gu + i * 32, beu + i * 32,
                                          resid, h_new, Wn, bn, st_next);
    }

    k_final_v18<<<782, blk, 0, stream>>>(RING[2], bf0, bf1, bf2, bf3, Wo, bo, out);
}

// Round 11
// 974.006 us; speedup vs baseline: 1.0896x; 1.0896x over previous
//
#include <hip/hip_runtime.h>
#include <hip/hip_bf16.h>

#define NN 100000
#define NEDGE 1600000
#define NV (NN*32)
#define NEG 0.01f
#define EPS 1e-5f
#define NBLK 391            // ceil(NN/256)
#define NBKT 391            // node buckets (256 nodes each)
#define CHUNK 4096          // edges per binning block
#define NCBLK 391           // ceil(NEDGE/CHUNK)
#define DCAP 6144           // LDS stage capacity in k_csr (mean 4096 + 32 sigma)
#define STC 64              // stat copies (contention spread)
#define ST_STRIDE 4096      // STC * 64
#define NGBLK 782           // ceil(NN/128) for dual-node fused gather+upd
#define NTILE 3125          // NN/32 tiles for k_nl

// ---- static device arena (fp32) ----
#define OFF_STATS 0
#define STATS_F  (22*ST_STRIDE)
#define OFF_PA   STATS_F
#define OFF_PB   (OFF_PA + NV)
#define OFF_TACT (OFF_PB + NV)           // post-act bf16 msgs
#define OFF_MSGB (OFF_TACT + NV)         // pre-act bf16 msgs
#define OFF_RING (OFF_MSGB + NV/2)
#define OFF_WF   (OFF_RING + 4*NV)       // bf16 weight frags for final MLP (51200 shorts)
#define ARENA_F  (OFF_WF + 25600)

// weight-frag section bases in uint4 (16B) units
#define W0B 0
#define W1B 1024
#define W2B 5120
#define W3B 6144

__device__ __align__(16) float gA[ARENA_F];
__device__ int g_rowptr[NN + 1];
__device__ int g_csr[NEDGE];
__device__ int g_bin[NEDGE];       // bucket-grouped packed edges: (src<<8)|dlocal
__device__ int g_bcnt[NBKT];
__device__ int g_boff[NBKT];
__device__ int g_btail[NBKT];

__device__ __forceinline__ float lrelu(float v) { return v > 0.f ? v : v * NEG; }
__device__ __forceinline__ unsigned short f2b(float v) {
    __hip_bfloat16 b = __float2bfloat16(v);
    return *reinterpret_cast<unsigned short*>(&b);
}
__device__ __forceinline__ float b2f(unsigned short u) {
    __hip_bfloat16 b = *reinterpret_cast<__hip_bfloat16*>(&u);
    return __bfloat162float(b);
}

// ---------------- zero stats + bucket counts ----------------
__global__ void k_zero_v19()
{
    int i = blockIdx.x * 256 + threadIdx.x;
    if (i < STATS_F) gA[i] = 0.f;
    if (i < NBKT) g_bcnt[i] = 0;
}

// ---------------- bucket histogram (LDS-staged, low-contention) ----------------
__global__ __launch_bounds__(256) void k_bcnt_v19(const int* __restrict__ col)
{
    __shared__ int hist[NBKT];
    int tid = threadIdx.x;
    for (int b = tid; b < NBKT; b += 256) hist[b] = 0;
    __syncthreads();
    int e0 = blockIdx.x * CHUNK;
    #pragma unroll
    for (int r = 0; r < CHUNK / 256; ++r) {
        int e = e0 + r * 256 + tid;
        if (e < NEDGE) atomicAdd(&hist[col[NEDGE + e] >> 8], 1);
    }
    __syncthreads();
    for (int b = tid; b < NBKT; b += 256) {
        int v = hist[b];
        if (v) atomicAdd(&g_bcnt[b], v);
    }
}

// ---------------- scan bucket counts -> offsets + tails ----------------
__global__ __launch_bounds__(512) void k_bscan_v19()
{
    __shared__ int s[512];
    int t = threadIdx.x;
    int v = (t < NBKT) ? g_bcnt[t] : 0;
    s[t] = v;
    __syncthreads();
    for (int off = 1; off < 512; off <<= 1) {
        int u = (t >= off) ? s[t - off] : 0;
        __syncthreads();
        s[t] += u;
        __syncthreads();
    }
    if (t < NBKT) {
        int o = s[t] - v;
        g_boff[t] = o;
        g_btail[t] = o;
    }
}

// ---------------- bin edges into bucket-contiguous regions (chunked append) ----------------
__global__ __launch_bounds__(256) void k_binfill_v19(const int* __restrict__ col)
{
    __shared__ int ssrc[CHUNK];
    __shared__ int sdst[CHUNK];
    __shared__ int hist[NBKT];
    __shared__ int boffL[NBKT];
    __shared__ int cnt2[NBKT];
    int tid = threadIdx.x;
    for (int b = tid; b < NBKT; b += 256) { hist[b] = 0; cnt2[b] = 0; }
    __syncthreads();
    int e0 = blockIdx.x * CHUNK;
    #pragma unroll
    for (int r = 0; r < CHUNK / 256; ++r) {
        int i = r * 256 + tid;
        int e = e0 + i;
        if (e < NEDGE) {
            int s = col[e];
            int d = col[NEDGE + e];
            ssrc[i] = s;
            sdst[i] = d;
            atomicAdd(&hist[d >> 8], 1);
        }
    }
    __syncthreads();
    for (int b = tid; b < NBKT; b += 256) {
        int h = hist[b];
        if (h) boffL[b] = atomicAdd(&g_btail[b], h);
    }
    __syncthreads();
    #pragma unroll
    for (int r = 0; r < CHUNK / 256; ++r) {
        int i = r * 256 + tid;
        int e = e0 + i;
        if (e < NEDGE) {
            int d = sdst[i];
            int b = d >> 8;
            int rk = atomicAdd(&cnt2[b], 1);
            g_bin[boffL[b] + rk] = (ssrc[i] << 8) | (d & 255);
        }
    }
}

// ------- per-bucket counting scatter -> CSR grouped by (node, src-segment) -------
__global__ __launch_bounds__(256) void k_csr_v24()
{
    __shared__ int stg[DCAP];
    __shared__ int c1[1024];     // [dlocal][seg] counts
    __shared__ int sgb[1024];    // [dlocal][seg] start within row
    __shared__ int c2[1024];     // scatter ranks
    __shared__ int sc[256];
    __shared__ int sl[256];
    int tid = threadIdx.x, b = blockIdx.x;
    int base = g_boff[b];
    int cntE = g_bcnt[b];
    #pragma unroll
    for (int k = 0; k < 4; ++k) { c1[tid + 256 * k] = 0; c2[tid + 256 * k] = 0; }
    __syncthreads();
    for (int i = tid; i < cntE; i += 256) {
        int p = g_bin[base + i];
        if (i < DCAP) stg[i] = p;
        atomicAdd(&c1[((p & 255) << 2) | (p >> 23)], 1);
    }
    __syncthreads();
    int t0 = c1[tid * 4], t1 = c1[tid * 4 + 1], t2 = c1[tid * 4 + 2], t3 = c1[tid * 4 + 3];
    int deg = t0 + t1 + t2 + t3;
    sgb[tid * 4]     = 0;
    sgb[tid * 4 + 1] = t0;
    sgb[tid * 4 + 2] = t0 + t1;
    sgb[tid * 4 + 3] = t0 + t1 + t2;
    sc[tid] = deg;
    __syncthreads();
    for (int off = 1; off < 256; off <<= 1) {
        int u = (tid >= off) ? sc[tid - off] : 0;
        __syncthreads();
        sc[tid] += u;
        __syncthreads();
    }
    int loff = sc[tid] - deg;
    sl[tid] = loff;
    int node = b * 256 + tid;
    if (node < NN) g_rowptr[node] = base + loff;
    if (b == NBKT - 1 && tid == 0) g_rowptr[NN] = NEDGE;
    __syncthreads();
    for (int i = tid; i < cntE; i += 256) {
        int p = (i < DCAP) ? stg[i] : g_bin[base + i];
        int dl = p & 255;
        int k2 = (dl << 2) | (p >> 23);
        int rk = atomicAdd(&c2[k2], 1);
        g_csr[base + sl[dl] + sgb[k2] + rk] = p >> 8;
    }
}

// ---------------- init layer 0: PA = x*Wi0 + bi0, stats ----------------
__global__ void k_init0_v17(const float* __restrict__ x, const float* __restrict__ Wi0,
                            const float* __restrict__ bi0)
{
    int j = threadIdx.x & 31, ns = threadIdx.x >> 5;
    float w = Wi0[j];
    float bb = bi0[j];
    __shared__ float red[64];
    if (threadIdx.x < 64) red[threadIdx.x] = 0.f;
    __syncthreads();
    float s1 = 0.f, s2 = 0.f;
    for (int t = blockIdx.x; t < NN / 8; t += gridDim.x) {
        int n = t * 8 + ns;
        float v = x[n] * w + bb;
        gA[OFF_PA + n * 32 + j] = v;
        s1 += v; s2 += v * v;
    }
    atomicAdd(&red[j], s1);
    atomicAdd(&red[j + 32], s2);
    __syncthreads();
    if (threadIdx.x < 64)
        atomicAdd(&gA[OFF_STATS + (blockIdx.x & (STC - 1)) * 64 + threadIdx.x], red[threadIdx.x]);
}

// ------- BN+LReLU (+resid) (+feats) (+fused 32x32 linear + stats), 32-node tiles -------
__global__ __launch_bounds__(256) void k_nl_v24(int off_in, int off_out, int out_msg, int st_in,
                         const float* __restrict__ gamma, const float* __restrict__ beta,
                         int off_resid, int off_feats,
                         const float* __restrict__ Wn, const float* __restrict__ bn,
                         int st_out)
{
    int tid = threadIdx.x;
    int j = tid & 31, grp = tid >> 5;
    __shared__ float sstat[64];
    __shared__ float red[64];
    __shared__ float sH[32][32];
    if (tid < 64) {
        red[tid] = 0.f;
        float acc = 0.f;
        int base = st_in + tid;
        #pragma unroll 8
        for (int c = 0; c < STC; ++c) acc += gA[base + c * 64];
        sstat[tid] = acc;
    }
    __syncthreads();
    float mean = sstat[j] * (1.f / NN);
    float var  = sstat[32 + j] * (1.f / NN) - mean * mean;
    float scale = gamma[j] * rsqrtf(var + EPS);
    float shift = beta[j] - mean * scale;

    float wc[32]; float bb = 0.f;
    if (Wn) {
        #pragma unroll
        for (int k = 0; k < 32; ++k) wc[k] = Wn[k * 32 + j];
        bb = bn[j];
    }
    unsigned short* mb = (unsigned short*)(gA + OFF_MSGB);
    float s1 = 0.f, s2 = 0.f;
    for (int t = blockIdx.x; t < NTILE; t += gridDim.x) {
        int base = t * 1024;
        #pragma unroll
        for (int k = 0; k < 4; ++k) {
            int idx = tid + 256 * k;
            float v = gA[off_in + base + idx];
            v = lrelu(scale * v + shift);
            if (off_resid >= 0) v += gA[off_resid + base + idx];
            if (off_feats >= 0) gA[off_feats + base + idx] = v;
            ((float*)sH)[idx] = v;
        }
        if (Wn) {
            __syncthreads();
            #pragma unroll
            for (int q = 0; q < 4; ++q) {
                int nl = grp * 4 + q;
                float acc = bb;
                #pragma unroll
                for (int k = 0; k < 32; k += 4) {
                    float4 h4 = *(const float4*)&sH[nl][k];
                    acc += h4.x * wc[k] + h4.y * wc[k + 1] + h4.z * wc[k + 2] + h4.w * wc[k + 3];
                }
                int n = t * 32 + nl;
                if (out_msg) mb[n * 32 + j] = f2b(acc);
                else gA[off_out + n * 32 + j] = acc;
                s1 += acc; s2 += acc * acc;
            }
            __syncthreads();
        }
    }
    if (Wn) {
        atomicAdd(&red[j], s1);
        atomicAdd(&red[j + 32], s2);
        __syncthreads();
        if (tid < 64)
            atomicAdd(&gA[st_out + (blockIdx.x & (STC - 1)) * 64 + tid], red[tid]);
    }
}

// ---- per-node post-activation: TACT = bf16(lrelu(BN(MSGB))) [node][32] ----
__global__ __launch_bounds__(256) void k_act_v21(int st_msg,
                                                 const float* __restrict__ gm,
                                                 const float* __restrict__ bem)
{
    __shared__ float sstat[64];
    __shared__ float scl[32], shf[32];
    int tid = threadIdx.x;
    if (tid < 64) {
        float acc = 0.f;
        int base = st_msg + tid;
        #pragma unroll 8
        for (int c = 0; c < STC; ++c) acc += gA[base + c * 64];
        sstat[tid] = acc;
    }
    __syncthreads();
    if (tid < 32) {
        float mean = sstat[tid] * (1.f / NN);
        float var  = sstat[32 + tid] * (1.f / NN) - mean * mean;
        float s = gm[tid] * rsqrtf(var + EPS);
        scl[tid] = s;
        shf[tid] = bem[tid] - mean * s;
    }
    __syncthreads();
    int idx = blockIdx.x * 256 + tid;          // uint4 index over NV/8
    if (idx >= NV / 8) return;
    const uint4* src = (const uint4*)(gA + OFF_MSGB);
    uint4* dst = (uint4*)(gA + OFF_TACT);
    uint4 m = src[idx];
    int fb = (idx & 3) * 8;
    uint4 o;
    #pragma unroll
    for (int w = 0; w < 4; ++w) {
        unsigned int u = (&m.x)[w];
        int f0 = fb + 2 * w;
        float vlo = lrelu(scl[f0]     * __uint_as_float(u << 16)         + shf[f0]);
        float vhi = lrelu(scl[f0 + 1] * __uint_as_float(u & 0xffff0000u) + shf[f0 + 1]);
        (&o.x)[w] = (unsigned int)f2b(vlo) | ((unsigned int)f2b(vhi) << 16);
    }
    dst[idx] = o;
}

// ======== fused gather + update GEMM, DUAL-NODE streams per lane (2x MLP) ========
// Each quad processes nodes (nl) and (nl+64) with interleaved 4-edge unrolls:
// 8 uint4 loads in flight per lane. Block covers 128 nodes. Per-feature
// summation order per node unchanged (ascending e) -> numerics identical.
__global__ __launch_bounds__(256) void k_gupd_v26(int off_h,
                                                  const float* __restrict__ Wu_i,
                                                  const float* __restrict__ bu_i,
                                                  int st_out)
{
    __shared__ float sH[128][36];
    __shared__ float sAgg[128][36];
    __shared__ float red[64];
    int tid = threadIdx.x;
    int nb = blockIdx.x * 128;

    if (tid < 64) red[tid] = 0.f;
    {
        const float* hp = gA + off_h + nb * 32;
        int lim = min(4096, (NN - nb) * 32);
        for (int idx = tid; idx < lim; idx += 256)
            sH[idx >> 5][idx & 31] = hp[idx];
    }

    // ---- phase A: dual-stream gather ----
    {
        int nl = tid >> 2;          // quad id 0..63 -> nodes nl and nl+64
        int g  = tid & 3;           // feature group (8 feats)
        int nA = nb + nl;
        int nB = nb + 64 + nl;
        float a[8], b[8];
        #pragma unroll
        for (int q = 0; q < 8; ++q) { a[q] = 0.f; b[q] = 0.f; }
        const unsigned short* tb = (const unsigned short*)(gA + OFF_TACT);
        int eA = 0, eA1 = 0, eB = 0, eB1 = 0;
        if (nA < NN) { eA = g_rowptr[nA]; eA1 = g_rowptr[nA + 1]; }
        if (nB < NN) { eB = g_rowptr[nB]; eB1 = g_rowptr[nB + 1]; }

        // dual 4-edge unrolled loop: 8 msg loads in flight
        for (; eA + 3 < eA1 && eB + 3 < eB1; eA += 4, eB += 4) {
            int sgA = g_csr[eA + g];
            int sgB = g_csr[eB + g];
            int a0 = __shfl(sgA, 0, 4), a1s = __shfl(sgA, 1, 4);
            int a2s = __shfl(sgA, 2, 4), a3s = __shfl(sgA, 3, 4);
            int b0 = __shfl(sgB, 0, 4), b1s = __shfl(sgB, 1, 4);
            int b2s = __shfl(sgB, 2, 4), b3s = __shfl(sgB, 3, 4);
            uint4 mA0 = *(const uint4*)(tb + (a0 << 5) + (g << 3));
            uint4 mA1 = *(const uint4*)(tb + (a1s << 5) + (g << 3));
            uint4 mA2 = *(const uint4*)(tb + (a2s << 5) + (g << 3));
            uint4 mA3 = *(const uint4*)(tb + (a3s << 5) + (g << 3));
            uint4 mB0 = *(const uint4*)(tb + (b0 << 5) + (g << 3));
            uint4 mB1 = *(const uint4*)(tb + (b1s << 5) + (g << 3));
            uint4 mB2 = *(const uint4*)(tb + (b2s << 5) + (g << 3));
            uint4 mB3 = *(const uint4*)(tb + (b3s << 5) + (g << 3));
            #pragma unroll
            for (int w = 0; w < 4; ++w) {
                int q = w * 2;
                unsigned int uA0 = (&mA0.x)[w], uA1 = (&mA1.x)[w], uA2 = (&mA2.x)[w], uA3 = (&mA3.x)[w];
                unsigned int uB0 = (&mB0.x)[w], uB1 = (&mB1.x)[w], uB2 = (&mB2.x)[w], uB3 = (&mB3.x)[w];
                a[q]   += __uint_as_float(uA0 << 16) + __uint_as_float(uA1 << 16)
                        + __uint_as_float(uA2 << 16) + __uint_as_float(uA3 << 16);
                a[q+1] += __uint_as_float(uA0 & 0xffff0000u) + __uint_as_float(uA1 & 0xffff0000u)
                        + __uint_as_float(uA2 & 0xffff0000u) + __uint_as_float(uA3 & 0xffff0000u);
                b[q]   += __uint_as_float(uB0 << 16) + __uint_as_float(uB1 << 16)
                        + __uint_as_float(uB2 << 16) + __uint_as_float(uB3 << 16);
                b[q+1] += __uint_as_float(uB0 & 0xffff0000u) + __uint_as_float(uB1 & 0xffff0000u)
                        + __uint_as_float(uB2 & 0xffff0000u) + __uint_as_float(uB3 & 0xffff0000u);
            }
        }
        // drain A (4-edge then singles)
        for (; eA + 3 < eA1; eA += 4) {
            int sg = g_csr[eA + g];
            int s0 = __shfl(sg, 0, 4), s1 = __shfl(sg, 1, 4);
            int s2 = __shfl(sg, 2, 4), s3 = __shfl(sg, 3, 4);
            uint4 m0 = *(const uint4*)(tb + (s0 << 5) + (g << 3));
            uint4 m1 = *(const uint4*)(tb + (s1 << 5) + (g << 3));
            uint4 m2 = *(const uint4*)(tb + (s2 << 5) + (g << 3));
            uint4 m3 = *(const uint4*)(tb + (s3 << 5) + (g << 3));
            #pragma unroll
            for (int w = 0; w < 4; ++w) {
                int q = w * 2;
                unsigned int u0 = (&m0.x)[w], u1 = (&m1.x)[w], u2 = (&m2.x)[w], u3 = (&m3.x)[w];
                a[q]   += __uint_as_float(u0 << 16) + __uint_as_float(u1 << 16)
                        + __uint_as_float(u2 << 16) + __uint_as_float(u3 << 16);
                a[q+1] += __uint_as_float(u0 & 0xffff0000u) + __uint_as_float(u1 & 0xffff0000u)
                        + __uint_as_float(u2 & 0xffff0000u) + __uint_as_float(u3 & 0xffff0000u);
            }
        }
        for (; eA < eA1; ++eA) {
            int s0 = g_csr[eA];
            uint4 m0 = *(const uint4*)(tb + (s0 << 5) + (g << 3));
            #pragma unroll
            for (int w = 0; w < 4; ++w) {
                int q = w * 2;
                unsigned int u0 = (&m0.x)[w];
                a[q]   += __uint_as_float(u0 << 16);
                a[q+1] += __uint_as_float(u0 & 0xffff0000u);
            }
        }
        // drain B (4-edge then singles)
        for (; eB + 3 < eB1; eB += 4) {
            int sg = g_csr[eB + g];
            int s0 = __shfl(sg, 0, 4), s1 = __shfl(sg, 1, 4);
            int s2 = __shfl(sg, 2, 4), s3 = __shfl(sg, 3, 4);
            uint4 m0 = *(const uint4*)(tb + (s0 << 5) + (g << 3));
            uint4 m1 = *(const uint4*)(tb + (s1 << 5) + (g << 3));
            uint4 m2 = *(const uint4*)(tb + (s2 << 5) + (g << 3));
            uint4 m3 = *(const uint4*)(tb + (s3 << 5) + (g << 3));
            #pragma unroll
            for (int w = 0; w < 4; ++w) {
                int q = w * 2;
                unsigned int u0 = (&m0.x)[w], u1 = (&m1.x)[w], u2 = (&m2.x)[w], u3 = (&m3.x)[w];
                b[q]   += __uint_as_float(u0 << 16) + __uint_as_float(u1 << 16)
                        + __uint_as_float(u2 << 16) + __uint_as_float(u3 << 16);
                b[q+1] += __uint_as_float(u0 & 0xffff0000u) + __uint_as_float(u1 & 0xffff0000u)
                        + __uint_as_float(u2 & 0xffff0000u) + __uint_as_float(u3 & 0xffff0000u);
            }
        }
        for (; eB < eB1; ++eB) {
            int s0 = g_csr[eB];
            uint4 m0 = *(const uint4*)(tb + (s0 << 5) + (g << 3));
            #pragma unroll
            for (int w = 0; w < 4; ++w) {
                int q = w * 2;
                unsigned int u0 = (&m0.x)[w];
                b[q]   += __uint_as_float(u0 << 16);
                b[q+1] += __uint_as_float(u0 & 0xffff0000u);
            }
        }
        *(float4*)&sAgg[nl][g * 8]          = make_float4(a[0], a[1], a[2], a[3]);
        *(float4*)&sAgg[nl][g * 8 + 4]      = make_float4(a[4], a[5], a[6], a[7]);
        *(float4*)&sAgg[nl + 64][g * 8]     = make_float4(b[0], b[1], b[2], b[3]);
        *(float4*)&sAgg[nl + 64][g * 8 + 4] = make_float4(b[4], b[5], b[6], b[7]);
    }
    __syncthreads();

    // ---- phase B: update GEMM (128 nodes) ----
    {
        int j = tid & 31, ns = tid >> 5;
        float wc[64];
        #pragma unroll
        for (int k = 0; k < 64; ++k) wc[k] = Wu_i[k * 32 + j];
        float bb = bu_i[j];
        float s1 = 0.f, s2 = 0.f;
        #pragma unroll
        for (int it = 0; it < 16; ++it) {
            int nl = it * 8 + ns;
            int n = nb + nl;
            if (n >= NN) break;
            float acc = bb;
            #pragma unroll
            for (int k = 0; k < 32; k += 4) {
                float4 h4 = *(const float4*)&sH[nl][k];
                acc += h4.x * wc[k] + h4.y * wc[k + 1] + h4.z * wc[k + 2] + h4.w * wc[k + 3];
                float4 a4 = *(const float4*)&sAgg[nl][k];
                acc += a4.x * wc[32 + k] + a4.y * wc[32 + k + 1] + a4.z * wc[32 + k + 2] + a4.w * wc[32 + k + 3];
            }
            gA[OFF_PB + n * 32 + j] = acc;
            s1 += acc; s2 += acc * acc;
        }
        atomicAdd(&red[j], s1);
        atomicAdd(&red[j + 32], s2);
        __syncthreads();
        if (tid < 64)
            atomicAdd(&gA[st_out + (blockIdx.x & (STC - 1)) * 64 + tid], red[tid]);
    }
}

// ================= MFMA final MLP =================
typedef __attribute__((ext_vector_type(8))) short bf16x8;
typedef __attribute__((ext_vector_type(4))) float f32x4;

union FC { uint4 u; bf16x8 b; };

#define MFMA(a, b, c) __builtin_amdgcn_mfma_f32_16x16x32_bf16(a, b, c, 0, 0, 0)

__device__ __forceinline__ bf16x8 ld_wf(const uint4* p) {
    FC c; c.u = *p; return c.b;
}

__device__ __forceinline__ f32x4 ld_bias4(const float* p) {
    float4 t = *(const float4*)p;
    f32x4 r; r[0] = t.x; r[1] = t.y; r[2] = t.z; r[3] = t.w; return r;
}

__device__ __forceinline__ f32x4 lrelu4(f32x4 v) {
    f32x4 r;
    #pragma unroll
    for (int k = 0; k < 4; ++k) r[k] = v[k] > 0.f ? v[k] : v[k] * NEG;
    return r;
}

__device__ __forceinline__ void splitpack(const float* v, bf16x8& hi, bf16x8& lo) {
    unsigned int h[4], l[4];
    #pragma unroll
    for (int k = 0; k < 4; ++k) {
        unsigned short h0 = f2b(v[2*k]), h1 = f2b(v[2*k+1]);
        float r0 = v[2*k]   - b2f(h0);
        float r1 = v[2*k+1] - b2f(h1);
        h[k] = (unsigned int)h0 | ((unsigned int)h1 << 16);
        l[k] = (unsigned int)f2b(r0) | ((unsigned int)f2b(r1) << 16);
    }
    FC ch; ch.u = make_uint4(h[0], h[1], h[2], h[3]); hi = ch.b;
    FC cl; cl.u = make_uint4(l[0], l[1], l[2], l[3]); lo = cl.b;
}

__global__ __launch_bounds__(256) void k_wprep_v18(const float* __restrict__ W0,
                                                   const float* __restrict__ W1,
                                                   const float* __restrict__ W2,
                                                   const float* __restrict__ W3)
{
    int i = blockIdx.x * 256 + threadIdx.x;
    if (i >= 51200) return;
    const float* src; int Nout, nk; int r = i;
    if (r < 8192)       { src = W0; Nout = 256; nk = 1; }
    else if (r < 40960) { src = W1; Nout = 128; nk = 8; r -= 8192; }
    else if (r < 49152) { src = W2; Nout = 64;  nk = 4; r -= 40960; }
    else                { src = W3; Nout = 32;  nk = 2; r -= 49152; }
    int frag = r >> 9;
    int lane = (r >> 3) & 63;
    int j = r & 7;
    int T = frag / nk, s = frag - T * nk;
    int g = lane >> 4;
    int outf = T * 16 + (lane & 15);
    int inf = 32 * s + 16 * (j >> 2) + 4 * g + (j & 3);
    unsigned short* dst = (unsigned short*)(gA + OFF_WF);
    dst[i] = f2b(src[inf * Nout + outf]);
}

__global__ __launch_bounds__(256) void k_final_v18(
    int off_h,
    const float* __restrict__ bf0, const float* __restrict__ bf1,
    const float* __restrict__ bf2, const float* __restrict__ bf3,
    const float* __restrict__ Wo,  const float* __restrict__ bo,
    float* __restrict__ out)
{
    int lane = threadIdx.x & 63;
    int wave = threadIdx.x >> 6;
    int c = lane & 15;
    int g = lane >> 4;
    int nb = blockIdx.x * 128 + wave * 32;
    int n0 = nb + c;
    int n1 = nb + 16 + c;
    int ld0 = min(n0, NN - 1), ld1 = min(n1, NN - 1);

    const float* h = gA + off_h;
    const uint4* WF = (const uint4*)(gA + OFF_WF);

    float4 ia0 = *(const float4*)&h[ld0 * 32 + 4 * g];
    float4 ib0 = *(const float4*)&h[ld0 * 32 + 16 + 4 * g];
    float4 ia1 = *(const float4*)&h[ld1 * 32 + 4 * g];
    float4 ib1 = *(const float4*)&h[ld1 * 32 + 16 + 4 * g];
    bf16x8 Bh0, Bl0, Bh1, Bl1;
    {
        float v0[8] = {ia0.x, ia0.y, ia0.z, ia0.w, ib0.x, ib0.y, ib0.z, ib0.w};
        float v1[8] = {ia1.x, ia1.y, ia1.z, ia1.w, ib1.x, ib1.y, ib1.z, ib1.w};
        splitpack(v0, Bh0, Bl0);
        splitpack(v1, Bh1, Bl1);
    }

    f32x4 A0[16][2];
    #pragma unroll
    for (int t = 0; t < 16; ++t) {
        f32x4 ci = ld_bias4(bf0 + t * 16 + 4 * g);
        bf16x8 w = ld_wf(WF + W0B + t * 64 + lane);
        f32x4 d0 = MFMA(w, Bh0, ci);
        d0 = MFMA(w, Bl0, d0);
        f32x4 d1 = MFMA(w, Bh1, ci);
        d1 = MFMA(w, Bl1, d1);
        A0[t][0] = lrelu4(d0);
        A0[t][1] = lrelu4(d1);
    }

    f32x4 A1[8][2];
    #pragma unroll
    for (int T = 0; T < 8; ++T) {
        f32x4 ci = ld_bias4(bf1 + T * 16 + 4 * g);
        A1[T][0] = ci; A1[T][1] = ci;
    }
    #pragma unroll
    for (int s = 0; s < 8; ++s) {
        bf16x8 bh[2], bl[2];
        #pragma unroll
        for (int u = 0; u < 2; ++u) {
            float vv[8] = {A0[2*s][u][0], A0[2*s][u][1], A0[2*s][u][2], A0[2*s][u][3],
                           A0[2*s+1][u][0], A0[2*s+1][u][1], A0[2*s+1][u][2], A0[2*s+1][u][3]};
            splitpack(vv, bh[u], bl[u]);
        }
        #pragma unroll
        for (int T = 0; T < 8; ++T) {
            bf16x8 w = ld_wf(WF + W1B + (T * 8 + s) * 64 + lane);
            A1[T][0] = MFMA(w, bh[0], A1[T][0]);
            A1[T][0] = MFMA(w, bl[0], A1[T][0]);
            A1[T][1] = MFMA(w, bh[1], A1[T][1]);
            A1[T][1] = MFMA(w, bl[1], A1[T][1]);
        }
    }
    #pragma unroll
    for (int T = 0; T < 8; ++T) { A1[T][0] = lrelu4(A1[T][0]); A1[T][1] = lrelu4(A1[T][1]); }

    f32x4 A2[4][2];
    #pragma unroll
    for (int T = 0; T < 4; ++T) {
        f32x4 ci = ld_bias4(bf2 + T * 16 + 4 * g);
        A2[T][0] = ci; A2[T][1] = ci;
    }
    #pragma unroll
    for (int s = 0; s < 4; ++s) {
        bf16x8 bh[2], bl[2];
        #pragma unroll
        for (int u = 0; u < 2; ++u) {
            float vv[8] = {A1[2*s][u][0], A1[2*s][u][1], A1[2*s][u][2], A1[2*s][u][3],
                           A1[2*s+1][u][0], A1[2*s+1][u][1], A1[2*s+1][u][2], A1[2*s+1][u][3]};
            splitpack(vv, bh[u], bl[u]);
        }
        #pragma unroll
        for (int T = 0; T < 4; ++T) {
            bf16x8 w = ld_wf(WF + W2B + (T * 4 + s) * 64 + lane);
            A2[T][0] = MFMA(w, bh[0], A2[T][0]);
            A2[T][0] = MFMA(w, bl[0], A2[T][0]);
            A2[T][1] = MFMA(w, bh[1], A2[T][1]);
            A2[T][1] = MFMA(w, bl[1], A2[T][1]);
        }
    }
    #pragma unroll
    for (int T = 0; T < 4; ++T) { A2[T][0] = lrelu4(A2[T][0]); A2[T][1] = lrelu4(A2[T][1]); }

    f32x4 A3[2][2];
    #pragma unroll
    for (int T = 0; T < 2; ++T) {
        f32x4 ci = ld_bias4(bf3 + T * 16 + 4 * g);
        A3[T][0] = ci; A3[T][1] = ci;
    }
    #pragma unroll
    for (int s = 0; s < 2; ++s) {
        bf16x8 bh[2], bl[2];
        #pragma unroll
        for (int u = 0; u < 2; ++u) {
            float vv[8] = {A2[2*s][u][0], A2[2*s][u][1], A2[2*s][u][2], A2[2*s][u][3],
                           A2[2*s+1][u][0], A2[2*s+1][u][1], A2[2*s+1][u][2], A2[2*s+1][u][3]};
            splitpack(vv, bh[u], bl[u]);
        }
        #pragma unroll
        for (int T = 0; T < 2; ++T) {
            bf16x8 w = ld_wf(WF + W3B + (T * 2 + s) * 64 + lane);
            A3[T][0] = MFMA(w, bh[0], A3[T][0]);
            A3[T][0] = MFMA(w, bl[0], A3[T][0]);
            A3[T][1] = MFMA(w, bh[1], A3[T][1]);
            A3[T][1] = MFMA(w, bl[1], A3[T][1]);
        }
    }
    #pragma unroll
    for (int T = 0; T < 2; ++T) { A3[T][0] = lrelu4(A3[T][0]); A3[T][1] = lrelu4(A3[T][1]); }

    float4 woa = *(const float4*)&Wo[4 * g];
    float4 wob = *(const float4*)&Wo[16 + 4 * g];
    float z0 = A3[0][0][0]*woa.x + A3[0][0][1]*woa.y + A3[0][0][2]*woa.z + A3[0][0][3]*woa.w
             + A3[1][0][0]*wob.x + A3[1][0][1]*wob.y + A3[1][0][2]*wob.z + A3[1][0][3]*wob.w;
    float z1 = A3[0][1][0]*woa.x + A3[0][1][1]*woa.y + A3[0][1][2]*woa.z + A3[0][1][3]*woa.w
             + A3[1][1][0]*wob.x + A3[1][1][1]*wob.y + A3[1][1][2]*wob.z + A3[1][1][3]*wob.w;
    z0 += __shfl_xor(z0, 16); z0 += __shfl_xor(z0, 32);
    z1 += __shfl_xor(z1, 16); z1 += __shfl_xor(z1, 32);
    float bb = bo[0];
    if (g == 0 && n0 < NN) out[n0] = 1.f / (1.f + __expf(-(z0 + bb)));
    if (g == 1 && n1 < NN) out[n1] = 1.f / (1.f + __expf(-(z1 + bb)));
}

extern "C" void kernel_launch(void* const* d_in, const int* in_sizes, int n_in,
                              void* d_out, int out_size, void* d_ws, size_t ws_size,
                              hipStream_t stream)
{
    (void)in_sizes; (void)n_in; (void)out_size; (void)d_ws; (void)ws_size;
    float* out = (float*)d_out;

    const float* x   = (const float*)d_in[0];
    const int*  col  = (const int*) d_in[1];
    const float* Wi0 = (const float*)d_in[2];
    const float* bi0 = (const float*)d_in[3];
    const float* gi0 = (const float*)d_in[4];
    const float* bei0= (const float*)d_in[5];
    const float* Wi1 = (const float*)d_in[6];
    const float* bi1 = (const float*)d_in[7];
    const float* gi1 = (const float*)d_in[8];
    const float* bei1= (const float*)d_in[9];
    const float* Wm  = (const float*)d_in[10];
    const float* bm  = (const float*)d_in[11];
    const float* gm  = (const float*)d_in[12];
    const float* bem = (const float*)d_in[13];
    const float* Wu  = (const float*)d_in[14];
    const float* bu  = (const float*)d_in[15];
    const float* gu  = (const float*)d_in[16];
    const float* beu = (const float*)d_in[17];
    const float* Wf0 = (const float*)d_in[18];
    const float* bf0 = (const float*)d_in[19];
    const float* Wf1 = (const float*)d_in[20];
    const float* bf1 = (const float*)d_in[21];
    const float* Wf2 = (const float*)d_in[22];
    const float* bf2 = (const float*)d_in[23];
    const float* Wf3 = (const float*)d_in[24];
    const float* bf3 = (const float*)d_in[25];
    const float* Wo  = (const float*)d_in[26];
    const float* bo  = (const float*)d_in[27];

    const int st_i0 = OFF_STATS;
    const int st_i1 = OFF_STATS + ST_STRIDE;
    const int st_m  = OFF_STATS + 2 * ST_STRIDE;    // + i*ST_STRIDE
    const int st_u  = OFF_STATS + 12 * ST_STRIDE;   // + i*ST_STRIDE

    const int RING[4] = { OFF_RING, OFF_RING + NV, OFF_RING + 2 * NV, OFF_RING + 3 * NV };

    dim3 blk(256);
    k_zero_v19<<<NBLK, blk, 0, stream>>>();
    k_bcnt_v19<<<NCBLK, blk, 0, stream>>>(col);
    k_bscan_v19<<<1, 512, 0, stream>>>();
    k_binfill_v19<<<NCBLK, blk, 0, stream>>>(col);
    k_csr_v24<<<NBKT, blk, 0, stream>>>();
    k_wprep_v18<<<200, blk, 0, stream>>>(Wf0, Wf1, Wf2, Wf3);

    // init MLP: x -> h0 (ring[0]); last k_nl chains layer-0 msg linear into bf16 MSGB
    k_init0_v17<<<1024, blk, 0, stream>>>(x, Wi0, bi0);
    k_nl_v24<<<782, blk, 0, stream>>>(OFF_PA, OFF_PB, 0, st_i0, gi0, bei0, -1, -1, Wi1, bi1, st_i1);
    k_nl_v24<<<782, blk, 0, stream>>>(OFF_PB, 0, 1, st_i1, gi1, bei1, -1, RING[0], Wm, bm, st_m);

    for (int i = 0; i < 10; ++i) {
        int h_cur = RING[i & 3];
        int h_new = RING[(i + 1) & 3];
        int resid = (i >= 2) ? RING[(i - 2) & 3] : -1;
        k_act_v21<<<1563, blk, 0, stream>>>(st_m + i * ST_STRIDE, gm + i * 32, bem + i * 32);
        k_gupd_v26<<<NGBLK, blk, 0, stream>>>(h_cur, Wu + i * 2048, bu + i * 32,
                                              st_u + i * ST_STRIDE);
        const float* Wn = (i < 9) ? (Wm + (i + 1) * 1024) : nullptr;
        const float* bn = (i < 9) ? (bm + (i + 1) * 32) : nullptr;
        int st_next = (i < 9) ? (st_m + (i + 1) * ST_STRIDE) : 0;
        k_nl_v24<<<782, blk, 0, stream>>>(OFF_PB, 0, 1, st_u + i * ST_STRIDE,
                                          gu + i * 32, beu + i * 32,
                                          resid, h_new, Wn, bn, st_next);
    }

    k_final_v18<<<782, blk, 0, stream>>>(RING[2], bf0, bf1, bf2, bf3, Wo, bo, out);
}

// Round 12
// 932.670 us; speedup vs baseline: 1.1379x; 1.0443x over previous
//
#include <hip/hip_runtime.h>
#include <hip/hip_bf16.h>

#define NN 100000
#define NEDGE 1600000
#define NV (NN*32)
#define NEG 0.01f
#define EPS 1e-5f
#define NBLK 391            // ceil(NN/256)
#define NBKT 391            // node buckets (256 nodes each)
#define CHUNK 4096          // edges per binning block
#define NCBLK 391           // ceil(NEDGE/CHUNK)
#define DCAP 6144           // LDS stage capacity in k_csr (mean 4096 + 32 sigma)
#define STC 64              // stat copies (contention spread)
#define ST_STRIDE 4096      // STC * 64
#define NGBLK 1563          // ceil(NN/64) for fused gather+upd
#define NTILE 3125          // NN/32 tiles for k_nl
#define CSRX (NEDGE + 302080)  // padded CSR capacity (align4 + 772/bucket)

// ---- static device arena (fp32) ----
#define OFF_STATS 0
#define STATS_F  (22*ST_STRIDE)
#define OFF_PA   STATS_F
#define OFF_PB   (OFF_PA + NV)
#define OFF_TACT (OFF_PB + NV)           // post-act bf16 msgs (NV shorts = rows 0..NN; row NN stays zero = sentinel)
#define OFF_MSGB (OFF_TACT + NV)         // pre-act bf16 msgs
#define OFF_RING (OFF_MSGB + NV/2)
#define OFF_WF   (OFF_RING + 4*NV)       // bf16 weight frags for final MLP (51200 shorts)
#define ARENA_F  (OFF_WF + 25600)

// weight-frag section bases in uint4 (16B) units
#define W0B 0
#define W1B 1024
#define W2B 5120
#define W3B 6144

__device__ __align__(16) float gA[ARENA_F];
__device__ int g_rowptr[NN + 1];
__device__ int g_rowend[NN];        // padded row end (start + pdeg)
__device__ __align__(16) int g_csr[CSRX];
__device__ int g_bin[NEDGE];       // bucket-grouped packed edges: (src<<8)|dlocal
__device__ int g_bcnt[NBKT];
__device__ int g_boff[NBKT];
__device__ int g_btail[NBKT];

__device__ __forceinline__ float lrelu(float v) { return v > 0.f ? v : v * NEG; }
__device__ __forceinline__ unsigned short f2b(float v) {
    __hip_bfloat16 b = __float2bfloat16(v);
    return *reinterpret_cast<unsigned short*>(&b);
}
__device__ __forceinline__ float b2f(unsigned short u) {
    __hip_bfloat16 b = *reinterpret_cast<__hip_bfloat16*>(&u);
    return __bfloat162float(b);
}

// ---------------- zero stats + bucket counts ----------------
__global__ void k_zero_v19()
{
    int i = blockIdx.x * 256 + threadIdx.x;
    if (i < STATS_F) gA[i] = 0.f;
    if (i < NBKT) g_bcnt[i] = 0;
}

// ---------------- bucket histogram (LDS-staged, low-contention) ----------------
__global__ __launch_bounds__(256) void k_bcnt_v19(const int* __restrict__ col)
{
    __shared__ int hist[NBKT];
    int tid = threadIdx.x;
    for (int b = tid; b < NBKT; b += 256) hist[b] = 0;
    __syncthreads();
    int e0 = blockIdx.x * CHUNK;
    #pragma unroll
    for (int r = 0; r < CHUNK / 256; ++r) {
        int e = e0 + r * 256 + tid;
        if (e < NEDGE) atomicAdd(&hist[col[NEDGE + e] >> 8], 1);
    }
    __syncthreads();
    for (int b = tid; b < NBKT; b += 256) {
        int v = hist[b];
        if (v) atomicAdd(&g_bcnt[b], v);
    }
}

// ---------------- scan bucket counts -> offsets + tails ----------------
__global__ __launch_bounds__(512) void k_bscan_v19()
{
    __shared__ int s[512];
    int t = threadIdx.x;
    int v = (t < NBKT) ? g_bcnt[t] : 0;
    s[t] = v;
    __syncthreads();
    for (int off = 1; off < 512; off <<= 1) {
        int u = (t >= off) ? s[t - off] : 0;
        __syncthreads();
        s[t] += u;
        __syncthreads();
    }
    if (t < NBKT) {
        int o = s[t] - v;
        g_boff[t] = o;
        g_btail[t] = o;
    }
}

// ---------------- bin edges into bucket-contiguous regions (chunked append) ----------------
__global__ __launch_bounds__(256) void k_binfill_v19(const int* __restrict__ col)
{
    __shared__ int ssrc[CHUNK];
    __shared__ int sdst[CHUNK];
    __shared__ int hist[NBKT];
    __shared__ int boffL[NBKT];
    __shared__ int cnt2[NBKT];
    int tid = threadIdx.x;
    for (int b = tid; b < NBKT; b += 256) { hist[b] = 0; cnt2[b] = 0; }
    __syncthreads();
    int e0 = blockIdx.x * CHUNK;
    #pragma unroll
    for (int r = 0; r < CHUNK / 256; ++r) {
        int i = r * 256 + tid;
        int e = e0 + i;
        if (e < NEDGE) {
            int s = col[e];
            int d = col[NEDGE + e];
            ssrc[i] = s;
            sdst[i] = d;
            atomicAdd(&hist[d >> 8], 1);
        }
    }
    __syncthreads();
    for (int b = tid; b < NBKT; b += 256) {
        int h = hist[b];
        if (h) boffL[b] = atomicAdd(&g_btail[b], h);
    }
    __syncthreads();
    #pragma unroll
    for (int r = 0; r < CHUNK / 256; ++r) {
        int i = r * 256 + tid;
        int e = e0 + i;
        if (e < NEDGE) {
            int d = sdst[i];
            int b = d >> 8;
            int rk = atomicAdd(&cnt2[b], 1);
            g_bin[boffL[b] + rk] = (ssrc[i] << 8) | (d & 255);
        }
    }
}

// ------- per-bucket counting scatter -> PADDED CSR (rows 16B-aligned, len%4==0) -------
// Pad slots hold sentinel src=NN (zero TACT row) -> gather needs no remainder loop.
__global__ __launch_bounds__(256) void k_csr_v27()
{
    __shared__ int stg[DCAP];
    __shared__ int c1[1024];     // [dlocal][seg] counts
    __shared__ int sgb[1024];    // [dlocal][seg] start within row
    __shared__ int c2[1024];     // scatter ranks
    __shared__ int sc[256];
    __shared__ int sl[256];
    int tid = threadIdx.x, b = blockIdx.x;
    int base = g_boff[b];
    int cntE = g_bcnt[b];
    int padbase = ((base + 3) & ~3) + 772 * b;
    #pragma unroll
    for (int k = 0; k < 4; ++k) { c1[tid + 256 * k] = 0; c2[tid + 256 * k] = 0; }
    __syncthreads();
    for (int i = tid; i < cntE; i += 256) {
        int p = g_bin[base + i];
        if (i < DCAP) stg[i] = p;
        atomicAdd(&c1[((p & 255) << 2) | (p >> 23)], 1);
    }
    __syncthreads();
    int t0 = c1[tid * 4], t1 = c1[tid * 4 + 1], t2 = c1[tid * 4 + 2], t3 = c1[tid * 4 + 3];
    int deg = t0 + t1 + t2 + t3;
    int pdeg = (deg + 3) & ~3;
    sgb[tid * 4]     = 0;
    sgb[tid * 4 + 1] = t0;
    sgb[tid * 4 + 2] = t0 + t1;
    sgb[tid * 4 + 3] = t0 + t1 + t2;
    sc[tid] = pdeg;
    __syncthreads();
    for (int off = 1; off < 256; off <<= 1) {
        int u = (tid >= off) ? sc[tid - off] : 0;
        __syncthreads();
        sc[tid] += u;
        __syncthreads();
    }
    int loff = sc[tid] - pdeg;
    sl[tid] = loff;
    int node = b * 256 + tid;
    if (node < NN) {
        g_rowptr[node] = padbase + loff;
        g_rowend[node] = padbase + loff + pdeg;
    }
    if (b == NBKT - 1 && tid == 0) g_rowptr[NN] = NEDGE;
    __syncthreads();
    for (int i = tid; i < cntE; i += 256) {
        int p = (i < DCAP) ? stg[i] : g_bin[base + i];
        int dl = p & 255;
        int k2 = (dl << 2) | (p >> 23);
        int rk = atomicAdd(&c2[k2], 1);
        g_csr[padbase + sl[dl] + sgb[k2] + rk] = p >> 8;
    }
    // fill pad slots with sentinel
    if (node < NN) {
        for (int k = deg; k < pdeg; ++k)
            g_csr[padbase + loff + k] = NN;
    }
}

// ---------------- init layer 0: PA = x*Wi0 + bi0, stats ----------------
__global__ void k_init0_v17(const float* __restrict__ x, const float* __restrict__ Wi0,
                            const float* __restrict__ bi0)
{
    int j = threadIdx.x & 31, ns = threadIdx.x >> 5;
    float w = Wi0[j];
    float bb = bi0[j];
    __shared__ float red[64];
    if (threadIdx.x < 64) red[threadIdx.x] = 0.f;
    __syncthreads();
    float s1 = 0.f, s2 = 0.f;
    for (int t = blockIdx.x; t < NN / 8; t += gridDim.x) {
        int n = t * 8 + ns;
        float v = x[n] * w + bb;
        gA[OFF_PA + n * 32 + j] = v;
        s1 += v; s2 += v * v;
    }
    atomicAdd(&red[j], s1);
    atomicAdd(&red[j + 32], s2);
    __syncthreads();
    if (threadIdx.x < 64)
        atomicAdd(&gA[OFF_STATS + (blockIdx.x & (STC - 1)) * 64 + threadIdx.x], red[threadIdx.x]);
}

// ------- BN+LReLU (+resid) (+feats) (+fused 32x32 linear + stats), 32-node tiles -------
__global__ __launch_bounds__(256) void k_nl_v24(int off_in, int off_out, int out_msg, int st_in,
                         const float* __restrict__ gamma, const float* __restrict__ beta,
                         int off_resid, int off_feats,
                         const float* __restrict__ Wn, const float* __restrict__ bn,
                         int st_out)
{
    int tid = threadIdx.x;
    int j = tid & 31, grp = tid >> 5;
    __shared__ float sstat[64];
    __shared__ float red[64];
    __shared__ float sH[32][32];
    if (tid < 64) {
        red[tid] = 0.f;
        float acc = 0.f;
        int base = st_in + tid;
        #pragma unroll 8
        for (int c = 0; c < STC; ++c) acc += gA[base + c * 64];
        sstat[tid] = acc;
    }
    __syncthreads();
    float mean = sstat[j] * (1.f / NN);
    float var  = sstat[32 + j] * (1.f / NN) - mean * mean;
    float scale = gamma[j] * rsqrtf(var + EPS);
    float shift = beta[j] - mean * scale;

    float wc[32]; float bb = 0.f;
    if (Wn) {
        #pragma unroll
        for (int k = 0; k < 32; ++k) wc[k] = Wn[k * 32 + j];
        bb = bn[j];
    }
    unsigned short* mb = (unsigned short*)(gA + OFF_MSGB);
    float s1 = 0.f, s2 = 0.f;
    for (int t = blockIdx.x; t < NTILE; t += gridDim.x) {
        int base = t * 1024;
        #pragma unroll
        for (int k = 0; k < 4; ++k) {
            int idx = tid + 256 * k;
            float v = gA[off_in + base + idx];
            v = lrelu(scale * v + shift);
            if (off_resid >= 0) v += gA[off_resid + base + idx];
            if (off_feats >= 0) gA[off_feats + base + idx] = v;
            ((float*)sH)[idx] = v;
        }
        if (Wn) {
            __syncthreads();
            #pragma unroll
            for (int q = 0; q < 4; ++q) {
                int nl = grp * 4 + q;
                float acc = bb;
                #pragma unroll
                for (int k = 0; k < 32; k += 4) {
                    float4 h4 = *(const float4*)&sH[nl][k];
                    acc += h4.x * wc[k] + h4.y * wc[k + 1] + h4.z * wc[k + 2] + h4.w * wc[k + 3];
                }
                int n = t * 32 + nl;
                if (out_msg) mb[n * 32 + j] = f2b(acc);
                else gA[off_out + n * 32 + j] = acc;
                s1 += acc; s2 += acc * acc;
            }
            __syncthreads();
        }
    }
    if (Wn) {
        atomicAdd(&red[j], s1);
        atomicAdd(&red[j + 32], s2);
        __syncthreads();
        if (tid < 64)
            atomicAdd(&gA[st_out + (blockIdx.x & (STC - 1)) * 64 + tid], red[tid]);
    }
}

// ---- per-node post-activation: TACT = bf16(lrelu(BN(MSGB))) [node][32]; row NN stays zero ----
__global__ __launch_bounds__(256) void k_act_v21(int st_msg,
                                                 const float* __restrict__ gm,
                                                 const float* __restrict__ bem)
{
    __shared__ float sstat[64];
    __shared__ float scl[32], shf[32];
    int tid = threadIdx.x;
    if (tid < 64) {
        float acc = 0.f;
        int base = st_msg + tid;
        #pragma unroll 8
        for (int c = 0; c < STC; ++c) acc += gA[base + c * 64];
        sstat[tid] = acc;
    }
    __syncthreads();
    if (tid < 32) {
        float mean = sstat[tid] * (1.f / NN);
        float var  = sstat[32 + tid] * (1.f / NN) - mean * mean;
        float s = gm[tid] * rsqrtf(var + EPS);
        scl[tid] = s;
        shf[tid] = bem[tid] - mean * s;
    }
    __syncthreads();
    int idx = blockIdx.x * 256 + tid;          // uint4 index over NV/8
    if (idx >= NV / 8) return;
    const uint4* src = (const uint4*)(gA + OFF_MSGB);
    uint4* dst = (uint4*)(gA + OFF_TACT);
    uint4 m = src[idx];
    int fb = (idx & 3) * 8;
    uint4 o;
    #pragma unroll
    for (int w = 0; w < 4; ++w) {
        unsigned int u = (&m.x)[w];
        int f0 = fb + 2 * w;
        float vlo = lrelu(scl[f0]     * __uint_as_float(u << 16)         + shf[f0]);
        float vhi = lrelu(scl[f0 + 1] * __uint_as_float(u & 0xffff0000u) + shf[f0 + 1]);
        (&o.x)[w] = (unsigned int)f2b(vlo) | ((unsigned int)f2b(vhi) << 16);
    }
    dst[idx] = o;
}

// ======== fused gather + update GEMM: padded rows, int4 index loads, 8-deep MLP ========
// Row start 16B-aligned, length %4==0 (sentinel src=NN -> zero row). Inner loop:
// 2x int4 csr loads (quad-broadcast, no shfl) + 8 independent uint4 msg loads.
#define ACC8(mm) { \
    unsigned int u_; \
    u_ = (mm).x; a[0] += __uint_as_float(u_ << 16); a[1] += __uint_as_float(u_ & 0xffff0000u); \
    u_ = (mm).y; a[2] += __uint_as_float(u_ << 16); a[3] += __uint_as_float(u_ & 0xffff0000u); \
    u_ = (mm).z; a[4] += __uint_as_float(u_ << 16); a[5] += __uint_as_float(u_ & 0xffff0000u); \
    u_ = (mm).w; a[6] += __uint_as_float(u_ << 16); a[7] += __uint_as_float(u_ & 0xffff0000u); }

__global__ __launch_bounds__(256) void k_gupd_v27(int off_h,
                                                  const float* __restrict__ Wu_i,
                                                  const float* __restrict__ bu_i,
                                                  int st_out)
{
    __shared__ float sH[64][36];
    __shared__ float sAgg[64][36];
    __shared__ float red[64];
    int tid = threadIdx.x;
    int nb = blockIdx.x * 64;

    if (tid < 64) red[tid] = 0.f;
    {
        const float* hp = gA + off_h + nb * 32;
        int lim = min(2048, (NN - nb) * 32);
        for (int idx = tid; idx < lim; idx += 256)
            sH[idx >> 5][idx & 31] = hp[idx];
    }

    // ---- phase A: gather (padded rows) ----
    {
        int nl = tid >> 2;          // local node 0..63
        int g  = tid & 3;           // feature group (8 feats)
        int n  = nb + nl;
        float a[8];
        #pragma unroll
        for (int q = 0; q < 8; ++q) a[q] = 0.f;
        if (n < NN) {
            const unsigned short* tb = (const unsigned short*)(gA + OFF_TACT);
            int e = g_rowptr[n], e1 = g_rowend[n];   // (e1-e)%4==0, e 16B-aligned
            for (; e + 7 < e1; e += 8) {
                int4 c0 = *(const int4*)(g_csr + e);
                int4 c1 = *(const int4*)(g_csr + e + 4);
                uint4 m0 = *(const uint4*)(tb + (c0.x << 5) + (g << 3));
                uint4 m1 = *(const uint4*)(tb + (c0.y << 5) + (g << 3));
                uint4 m2 = *(const uint4*)(tb + (c0.z << 5) + (g << 3));
                uint4 m3 = *(const uint4*)(tb + (c0.w << 5) + (g << 3));
                uint4 m4 = *(const uint4*)(tb + (c1.x << 5) + (g << 3));
                uint4 m5 = *(const uint4*)(tb + (c1.y << 5) + (g << 3));
                uint4 m6 = *(const uint4*)(tb + (c1.z << 5) + (g << 3));
                uint4 m7 = *(const uint4*)(tb + (c1.w << 5) + (g << 3));
                ACC8(m0) ACC8(m1) ACC8(m2) ACC8(m3)
                ACC8(m4) ACC8(m5) ACC8(m6) ACC8(m7)
            }
            if (e < e1) {                            // exactly 4 remain
                int4 c0 = *(const int4*)(g_csr + e);
                uint4 m0 = *(const uint4*)(tb + (c0.x << 5) + (g << 3));
                uint4 m1 = *(const uint4*)(tb + (c0.y << 5) + (g << 3));
                uint4 m2 = *(const uint4*)(tb + (c0.z << 5) + (g << 3));
                uint4 m3 = *(const uint4*)(tb + (c0.w << 5) + (g << 3));
                ACC8(m0) ACC8(m1) ACC8(m2) ACC8(m3)
            }
        }
        *(float4*)&sAgg[nl][g * 8]     = make_float4(a[0], a[1], a[2], a[3]);
        *(float4*)&sAgg[nl][g * 8 + 4] = make_float4(a[4], a[5], a[6], a[7]);
    }
    __syncthreads();

    // ---- phase B: update GEMM ----
    {
        int j = tid & 31, ns = tid >> 5;
        float wc[64];
        #pragma unroll
        for (int k = 0; k < 64; ++k) wc[k] = Wu_i[k * 32 + j];
        float bb = bu_i[j];
        float s1 = 0.f, s2 = 0.f;
        #pragma unroll
        for (int it = 0; it < 8; ++it) {
            int nl = it * 8 + ns;
            int n = nb + nl;
            if (n >= NN) break;
            float acc = bb;
            #pragma unroll
            for (int k = 0; k < 32; k += 4) {
                float4 h4 = *(const float4*)&sH[nl][k];
                acc += h4.x * wc[k] + h4.y * wc[k + 1] + h4.z * wc[k + 2] + h4.w * wc[k + 3];
                float4 a4 = *(const float4*)&sAgg[nl][k];
                acc += a4.x * wc[32 + k] + a4.y * wc[32 + k + 1] + a4.z * wc[32 + k + 2] + a4.w * wc[32 + k + 3];
            }
            gA[OFF_PB + n * 32 + j] = acc;
            s1 += acc; s2 += acc * acc;
        }
        atomicAdd(&red[j], s1);
        atomicAdd(&red[j + 32], s2);
        __syncthreads();
        if (tid < 64)
            atomicAdd(&gA[st_out + (blockIdx.x & (STC - 1)) * 64 + tid], red[tid]);
    }
}

// ================= MFMA final MLP =================
typedef __attribute__((ext_vector_type(8))) short bf16x8;
typedef __attribute__((ext_vector_type(4))) float f32x4;

union FC { uint4 u; bf16x8 b; };

#define MFMA(a, b, c) __builtin_amdgcn_mfma_f32_16x16x32_bf16(a, b, c, 0, 0, 0)

__device__ __forceinline__ bf16x8 ld_wf(const uint4* p) {
    FC c; c.u = *p; return c.b;
}

__device__ __forceinline__ f32x4 ld_bias4(const float* p) {
    float4 t = *(const float4*)p;
    f32x4 r; r[0] = t.x; r[1] = t.y; r[2] = t.z; r[3] = t.w; return r;
}

__device__ __forceinline__ f32x4 lrelu4(f32x4 v) {
    f32x4 r;
    #pragma unroll
    for (int k = 0; k < 4; ++k) r[k] = v[k] > 0.f ? v[k] : v[k] * NEG;
    return r;
}

__device__ __forceinline__ void splitpack(const float* v, bf16x8& hi, bf16x8& lo) {
    unsigned int h[4], l[4];
    #pragma unroll
    for (int k = 0; k < 4; ++k) {
        unsigned short h0 = f2b(v[2*k]), h1 = f2b(v[2*k+1]);
        float r0 = v[2*k]   - b2f(h0);
        float r1 = v[2*k+1] - b2f(h1);
        h[k] = (unsigned int)h0 | ((unsigned int)h1 << 16);
        l[k] = (unsigned int)f2b(r0) | ((unsigned int)f2b(r1) << 16);
    }
    FC ch; ch.u = make_uint4(h[0], h[1], h[2], h[3]); hi = ch.b;
    FC cl; cl.u = make_uint4(l[0], l[1], l[2], l[3]); lo = cl.b;
}

__global__ __launch_bounds__(256) void k_wprep_v18(const float* __restrict__ W0,
                                                   const float* __restrict__ W1,
                                                   const float* __restrict__ W2,
                                                   const float* __restrict__ W3)
{
    int i = blockIdx.x * 256 + threadIdx.x;
    if (i >= 51200) return;
    const float* src; int Nout, nk; int r = i;
    if (r < 8192)       { src = W0; Nout = 256; nk = 1; }
    else if (r < 40960) { src = W1; Nout = 128; nk = 8; r -= 8192; }
    else if (r < 49152) { src = W2; Nout = 64;  nk = 4; r -= 40960; }
    else                { src = W3; Nout = 32;  nk = 2; r -= 49152; }
    int frag = r >> 9;
    int lane = (r >> 3) & 63;
    int j = r & 7;
    int T = frag / nk, s = frag - T * nk;
    int g = lane >> 4;
    int outf = T * 16 + (lane & 15);
    int inf = 32 * s + 16 * (j >> 2) + 4 * g + (j & 3);
    unsigned short* dst = (unsigned short*)(gA + OFF_WF);
    dst[i] = f2b(src[inf * Nout + outf]);
}

__global__ __launch_bounds__(256) void k_final_v18(
    int off_h,
    const float* __restrict__ bf0, const float* __restrict__ bf1,
    const float* __restrict__ bf2, const float* __restrict__ bf3,
    const float* __restrict__ Wo,  const float* __restrict__ bo,
    float* __restrict__ out)
{
    int lane = threadIdx.x & 63;
    int wave = threadIdx.x >> 6;
    int c = lane & 15;
    int g = lane >> 4;
    int nb = blockIdx.x * 128 + wave * 32;
    int n0 = nb + c;
    int n1 = nb + 16 + c;
    int ld0 = min(n0, NN - 1), ld1 = min(n1, NN - 1);

    const float* h = gA + off_h;
    const uint4* WF = (const uint4*)(gA + OFF_WF);

    float4 ia0 = *(const float4*)&h[ld0 * 32 + 4 * g];
    float4 ib0 = *(const float4*)&h[ld0 * 32 + 16 + 4 * g];
    float4 ia1 = *(const float4*)&h[ld1 * 32 + 4 * g];
    float4 ib1 = *(const float4*)&h[ld1 * 32 + 16 + 4 * g];
    bf16x8 Bh0, Bl0, Bh1, Bl1;
    {
        float v0[8] = {ia0.x, ia0.y, ia0.z, ia0.w, ib0.x, ib0.y, ib0.z, ib0.w};
        float v1[8] = {ia1.x, ia1.y, ia1.z, ia1.w, ib1.x, ib1.y, ib1.z, ib1.w};
        splitpack(v0, Bh0, Bl0);
        splitpack(v1, Bh1, Bl1);
    }

    f32x4 A0[16][2];
    #pragma unroll
    for (int t = 0; t < 16; ++t) {
        f32x4 ci = ld_bias4(bf0 + t * 16 + 4 * g);
        bf16x8 w = ld_wf(WF + W0B + t * 64 + lane);
        f32x4 d0 = MFMA(w, Bh0, ci);
        d0 = MFMA(w, Bl0, d0);
        f32x4 d1 = MFMA(w, Bh1, ci);
        d1 = MFMA(w, Bl1, d1);
        A0[t][0] = lrelu4(d0);
        A0[t][1] = lrelu4(d1);
    }

    f32x4 A1[8][2];
    #pragma unroll
    for (int T = 0; T < 8; ++T) {
        f32x4 ci = ld_bias4(bf1 + T * 16 + 4 * g);
        A1[T][0] = ci; A1[T][1] = ci;
    }
    #pragma unroll
    for (int s = 0; s < 8; ++s) {
        bf16x8 bh[2], bl[2];
        #pragma unroll
        for (int u = 0; u < 2; ++u) {
            float vv[8] = {A0[2*s][u][0], A0[2*s][u][1], A0[2*s][u][2], A0[2*s][u][3],
                           A0[2*s+1][u][0], A0[2*s+1][u][1], A0[2*s+1][u][2], A0[2*s+1][u][3]};
            splitpack(vv, bh[u], bl[u]);
        }
        #pragma unroll
        for (int T = 0; T < 8; ++T) {
            bf16x8 w = ld_wf(WF + W1B + (T * 8 + s) * 64 + lane);
            A1[T][0] = MFMA(w, bh[0], A1[T][0]);
            A1[T][0] = MFMA(w, bl[0], A1[T][0]);
            A1[T][1] = MFMA(w, bh[1], A1[T][1]);
            A1[T][1] = MFMA(w, bl[1], A1[T][1]);
        }
    }
    #pragma unroll
    for (int T = 0; T < 8; ++T) { A1[T][0] = lrelu4(A1[T][0]); A1[T][1] = lrelu4(A1[T][1]); }

    f32x4 A2[4][2];
    #pragma unroll
    for (int T = 0; T < 4; ++T) {
        f32x4 ci = ld_bias4(bf2 + T * 16 + 4 * g);
        A2[T][0] = ci; A2[T][1] = ci;
    }
    #pragma unroll
    for (int s = 0; s < 4; ++s) {
        bf16x8 bh[2], bl[2];
        #pragma unroll
        for (int u = 0; u < 2; ++u) {
            float vv[8] = {A1[2*s][u][0], A1[2*s][u][1], A1[2*s][u][2], A1[2*s][u][3],
                           A1[2*s+1][u][0], A1[2*s+1][u][1], A1[2*s+1][u][2], A1[2*s+1][u][3]};
            splitpack(vv, bh[u], bl[u]);
        }
        #pragma unroll
        for (int T = 0; T < 4; ++T) {
            bf16x8 w = ld_wf(WF + W2B + (T * 4 + s) * 64 + lane);
            A2[T][0] = MFMA(w, bh[0], A2[T][0]);
            A2[T][0] = MFMA(w, bl[0], A2[T][0]);
            A2[T][1] = MFMA(w, bh[1], A2[T][1]);
            A2[T][1] = MFMA(w, bl[1], A2[T][1]);
        }
    }
    #pragma unroll
    for (int T = 0; T < 4; ++T) { A2[T][0] = lrelu4(A2[T][0]); A2[T][1] = lrelu4(A2[T][1]); }

    f32x4 A3[2][2];
    #pragma unroll
    for (int T = 0; T < 2; ++T) {
        f32x4 ci = ld_bias4(bf3 + T * 16 + 4 * g);
        A3[T][0] = ci; A3[T][1] = ci;
    }
    #pragma unroll
    for (int s = 0; s < 2; ++s) {
        bf16x8 bh[2], bl[2];
        #pragma unroll
        for (int u = 0; u < 2; ++u) {
            float vv[8] = {A2[2*s][u][0], A2[2*s][u][1], A2[2*s][u][2], A2[2*s][u][3],
                           A2[2*s+1][u][0], A2[2*s+1][u][1], A2[2*s+1][u][2], A2[2*s+1][u][3]};
            splitpack(vv, bh[u], bl[u]);
        }
        #pragma unroll
        for (int T = 0; T < 2; ++T) {
            bf16x8 w = ld_wf(WF + W3B + (T * 2 + s) * 64 + lane);
            A3[T][0] = MFMA(w, bh[0], A3[T][0]);
            A3[T][0] = MFMA(w, bl[0], A3[T][0]);
            A3[T][1] = MFMA(w, bh[1], A3[T][1]);
            A3[T][1] = MFMA(w, bl[1], A3[T][1]);
        }
    }
    #pragma unroll
    for (int T = 0; T < 2; ++T) { A3[T][0] = lrelu4(A3[T][0]); A3[T][1] = lrelu4(A3[T][1]); }

    float4 woa = *(const float4*)&Wo[4 * g];
    float4 wob = *(const float4*)&Wo[16 + 4 * g];
    float z0 = A3[0][0][0]*woa.x + A3[0][0][1]*woa.y + A3[0][0][2]*woa.z + A3[0][0][3]*woa.w
             + A3[1][0][0]*wob.x + A3[1][0][1]*wob.y + A3[1][0][2]*wob.z + A3[1][0][3]*wob.w;
    float z1 = A3[0][1][0]*woa.x + A3[0][1][1]*woa.y + A3[0][1][2]*woa.z + A3[0][1][3]*woa.w
             + A3[1][1][0]*wob.x + A3[1][1][1]*wob.y + A3[1][1][2]*wob.z + A3[1][1][3]*wob.w;
    z0 += __shfl_xor(z0, 16); z0 += __shfl_xor(z0, 32);
    z1 += __shfl_xor(z1, 16); z1 += __shfl_xor(z1, 32);
    float bb = bo[0];
    if (g == 0 && n0 < NN) out[n0] = 1.f / (1.f + __expf(-(z0 + bb)));
    if (g == 1 && n1 < NN) out[n1] = 1.f / (1.f + __expf(-(z1 + bb)));
}

extern "C" void kernel_launch(void* const* d_in, const int* in_sizes, int n_in,
                              void* d_out, int out_size, void* d_ws, size_t ws_size,
                              hipStream_t stream)
{
    (void)in_sizes; (void)n_in; (void)out_size; (void)d_ws; (void)ws_size;
    float* out = (float*)d_out;

    const float* x   = (const float*)d_in[0];
    const int*  col  = (const int*) d_in[1];
    const float* Wi0 = (const float*)d_in[2];
    const float* bi0 = (const float*)d_in[3];
    const float* gi0 = (const float*)d_in[4];
    const float* bei0= (const float*)d_in[5];
    const float* Wi1 = (const float*)d_in[6];
    const float* bi1 = (const float*)d_in[7];
    const float* gi1 = (const float*)d_in[8];
    const float* bei1= (const float*)d_in[9];
    const float* Wm  = (const float*)d_in[10];
    const float* bm  = (const float*)d_in[11];
    const float* gm  = (const float*)d_in[12];
    const float* bem = (const float*)d_in[13];
    const float* Wu  = (const float*)d_in[14];
    const float* bu  = (const float*)d_in[15];
    const float* gu  = (const float*)d_in[16];
    const float* beu = (const float*)d_in[17];
    const float* Wf0 = (const float*)d_in[18];
    const float* bf0 = (const float*)d_in[19];
    const float* Wf1 = (const float*)d_in[20];
    const float* bf1 = (const float*)d_in[21];
    const float* Wf2 = (const float*)d_in[22];
    const float* bf2 = (const float*)d_in[23];
    const float* Wf3 = (const float*)d_in[24];
    const float* bf3 = (const float*)d_in[25];
    const float* Wo  = (const float*)d_in[26];
    const float* bo  = (const float*)d_in[27];

    const int st_i0 = OFF_STATS;
    const int st_i1 = OFF_STATS + ST_STRIDE;
    const int st_m  = OFF_STATS + 2 * ST_STRIDE;    // + i*ST_STRIDE
    const int st_u  = OFF_STATS + 12 * ST_STRIDE;   // + i*ST_STRIDE

    const int RING[4] = { OFF_RING, OFF_RING + NV, OFF_RING + 2 * NV, OFF_RING + 3 * NV };

    dim3 blk(256);
    k_zero_v19<<<NBLK, blk, 0, stream>>>();
    k_bcnt_v19<<<NCBLK, blk, 0, stream>>>(col);
    k_bscan_v19<<<1, 512, 0, stream>>>();
    k_binfill_v19<<<NCBLK, blk, 0, stream>>>(col);
    k_csr_v27<<<NBKT, blk, 0, stream>>>();
    k_wprep_v18<<<200, blk, 0, stream>>>(Wf0, Wf1, Wf2, Wf3);

    // init MLP: x -> h0 (ring[0]); last k_nl chains layer-0 msg linear into bf16 MSGB
    k_init0_v17<<<1024, blk, 0, stream>>>(x, Wi0, bi0);
    k_nl_v24<<<782, blk, 0, stream>>>(OFF_PA, OFF_PB, 0, st_i0, gi0, bei0, -1, -1, Wi1, bi1, st_i1);
    k_nl_v24<<<782, blk, 0, stream>>>(OFF_PB, 0, 1, st_i1, gi1, bei1, -1, RING[0], Wm, bm, st_m);

    for (int i = 0; i < 10; ++i) {
        int h_cur = RING[i & 3];
        int h_new = RING[(i + 1) & 3];
        int resid = (i >= 2) ? RING[(i - 2) & 3] : -1;
        k_act_v21<<<1563, blk, 0, stream>>>(st_m + i * ST_STRIDE, gm + i * 32, bem + i * 32);
        k_gupd_v27<<<NGBLK, blk, 0, stream>>>(h_cur, Wu + i * 2048, bu + i * 32,
                                              st_u + i * ST_STRIDE);
        const float* Wn = (i < 9) ? (Wm + (i + 1) * 1024) : nullptr;
        const float* bn = (i < 9) ? (bm + (i + 1) * 32) : nullptr;
        int st_next = (i < 9) ? (st_m + (i + 1) * ST_STRIDE) : 0;
        k_nl_v24<<<782, blk, 0, stream>>>(OFF_PB, 0, 1, st_u + i * ST_STRIDE,
                                          gu + i * 32, beu + i * 32,
                                          resid, h_new, Wn, bn, st_next);
    }

    k_final_v18<<<782, blk, 0, stream>>>(RING[2], bf0, bf1, bf2, bf3, Wo, bo, out);
}

// Round 13
// 900.614 us; speedup vs baseline: 1.1784x; 1.0356x over previous
//
#include <hip/hip_runtime.h>
#include <hip/hip_bf16.h>

#define NN 100000
#define NEDGE 1600000
#define NV (NN*32)
#define NEG 0.01f
#define EPS 1e-5f
#define NBLK 391            // ceil(NN/256)
#define NBKT 391            // node buckets (256 nodes each)
#define CHUNK 4096          // edges per binning block
#define NCBLK 391           // ceil(NEDGE/CHUNK)
#define DCAP 6144           // LDS stage capacity in k_csr (mean 4096 + 32 sigma)
#define STC 64              // stat copies (contention spread)
#define ST_STRIDE 4096      // STC * 64
#define NGBLK 6250          // ceil(NN/16) 1-wave gather blocks
#define NTILE 3125          // NN/32 tiles for k_nl
#define CSRX (NEDGE + 302080)  // padded CSR capacity (align4 + 772/bucket)

// ---- static device arena (fp32) ----
#define OFF_STATS 0
#define STATS_F  (22*ST_STRIDE)
#define OFF_PA   STATS_F
#define OFF_PB   (OFF_PA + NV)
#define OFF_TACT (OFF_PB + NV)           // post-act bf16 msgs (rows 0..NN; row NN stays zero = sentinel)
#define OFF_MSGB (OFF_TACT + NV)         // pre-act bf16 msgs
#define OFF_RING (OFF_MSGB + NV/2)
#define OFF_WF   (OFF_RING + 4*NV)       // bf16 weight frags for final MLP (51200 shorts)
#define ARENA_F  (OFF_WF + 25600)

// weight-frag section bases in uint4 (16B) units
#define W0B 0
#define W1B 1024
#define W2B 5120
#define W3B 6144

__device__ __align__(16) float gA[ARENA_F];
__device__ int g_rowptr[NN + 1];
__device__ int g_rowend[NN];        // padded row end (start + pdeg)
__device__ __align__(16) int g_csr[CSRX];
__device__ int g_bin[NEDGE];       // bucket-grouped packed edges: (src<<8)|dlocal
__device__ int g_bcnt[NBKT];
__device__ int g_boff[NBKT];
__device__ int g_btail[NBKT];

__device__ __forceinline__ float lrelu(float v) { return v > 0.f ? v : v * NEG; }
__device__ __forceinline__ unsigned short f2b(float v) {
    __hip_bfloat16 b = __float2bfloat16(v);
    return *reinterpret_cast<unsigned short*>(&b);
}
__device__ __forceinline__ float b2f(unsigned short u) {
    __hip_bfloat16 b = *reinterpret_cast<__hip_bfloat16*>(&u);
    return __bfloat162float(b);
}

// ---------------- zero stats + bucket counts ----------------
__global__ void k_zero_v19()
{
    int i = blockIdx.x * 256 + threadIdx.x;
    if (i < STATS_F) gA[i] = 0.f;
    if (i < NBKT) g_bcnt[i] = 0;
}

// ---------------- bucket histogram (LDS-staged, low-contention) ----------------
__global__ __launch_bounds__(256) void k_bcnt_v19(const int* __restrict__ col)
{
    __shared__ int hist[NBKT];
    int tid = threadIdx.x;
    for (int b = tid; b < NBKT; b += 256) hist[b] = 0;
    __syncthreads();
    int e0 = blockIdx.x * CHUNK;
    #pragma unroll
    for (int r = 0; r < CHUNK / 256; ++r) {
        int e = e0 + r * 256 + tid;
        if (e < NEDGE) atomicAdd(&hist[col[NEDGE + e] >> 8], 1);
    }
    __syncthreads();
    for (int b = tid; b < NBKT; b += 256) {
        int v = hist[b];
        if (v) atomicAdd(&g_bcnt[b], v);
    }
}

// ---------------- scan bucket counts -> offsets + tails ----------------
__global__ __launch_bounds__(512) void k_bscan_v19()
{
    __shared__ int s[512];
    int t = threadIdx.x;
    int v = (t < NBKT) ? g_bcnt[t] : 0;
    s[t] = v;
    __syncthreads();
    for (int off = 1; off < 512; off <<= 1) {
        int u = (t >= off) ? s[t - off] : 0;
        __syncthreads();
        s[t] += u;
        __syncthreads();
    }
    if (t < NBKT) {
        int o = s[t] - v;
        g_boff[t] = o;
        g_btail[t] = o;
    }
}

// ---------------- bin edges into bucket-contiguous regions (chunked append) ----------------
__global__ __launch_bounds__(256) void k_binfill_v19(const int* __restrict__ col)
{
    __shared__ int ssrc[CHUNK];
    __shared__ int sdst[CHUNK];
    __shared__ int hist[NBKT];
    __shared__ int boffL[NBKT];
    __shared__ int cnt2[NBKT];
    int tid = threadIdx.x;
    for (int b = tid; b < NBKT; b += 256) { hist[b] = 0; cnt2[b] = 0; }
    __syncthreads();
    int e0 = blockIdx.x * CHUNK;
    #pragma unroll
    for (int r = 0; r < CHUNK / 256; ++r) {
        int i = r * 256 + tid;
        int e = e0 + i;
        if (e < NEDGE) {
            int s = col[e];
            int d = col[NEDGE + e];
            ssrc[i] = s;
            sdst[i] = d;
            atomicAdd(&hist[d >> 8], 1);
        }
    }
    __syncthreads();
    for (int b = tid; b < NBKT; b += 256) {
        int h = hist[b];
        if (h) boffL[b] = atomicAdd(&g_btail[b], h);
    }
    __syncthreads();
    #pragma unroll
    for (int r = 0; r < CHUNK / 256; ++r) {
        int i = r * 256 + tid;
        int e = e0 + i;
        if (e < NEDGE) {
            int d = sdst[i];
            int b = d >> 8;
            int rk = atomicAdd(&cnt2[b], 1);
            g_bin[boffL[b] + rk] = (ssrc[i] << 8) | (d & 255);
        }
    }
}

// ------- per-bucket counting scatter -> PADDED CSR (rows 16B-aligned, len%4==0) -------
// Pad slots hold sentinel src=NN (zero TACT row) -> gather needs no remainder loop.
__global__ __launch_bounds__(256) void k_csr_v27()
{
    __shared__ int stg[DCAP];
    __shared__ int c1[1024];     // [dlocal][seg] counts
    __shared__ int sgb[1024];    // [dlocal][seg] start within row
    __shared__ int c2[1024];     // scatter ranks
    __shared__ int sc[256];
    __shared__ int sl[256];
    int tid = threadIdx.x, b = blockIdx.x;
    int base = g_boff[b];
    int cntE = g_bcnt[b];
    int padbase = ((base + 3) & ~3) + 772 * b;
    #pragma unroll
    for (int k = 0; k < 4; ++k) { c1[tid + 256 * k] = 0; c2[tid + 256 * k] = 0; }
    __syncthreads();
    for (int i = tid; i < cntE; i += 256) {
        int p = g_bin[base + i];
        if (i < DCAP) stg[i] = p;
        atomicAdd(&c1[((p & 255) << 2) | (p >> 23)], 1);
    }
    __syncthreads();
    int t0 = c1[tid * 4], t1 = c1[tid * 4 + 1], t2 = c1[tid * 4 + 2], t3 = c1[tid * 4 + 3];
    int deg = t0 + t1 + t2 + t3;
    int pdeg = (deg + 3) & ~3;
    sgb[tid * 4]     = 0;
    sgb[tid * 4 + 1] = t0;
    sgb[tid * 4 + 2] = t0 + t1;
    sgb[tid * 4 + 3] = t0 + t1 + t2;
    sc[tid] = pdeg;
    __syncthreads();
    for (int off = 1; off < 256; off <<= 1) {
        int u = (tid >= off) ? sc[tid - off] : 0;
        __syncthreads();
        sc[tid] += u;
        __syncthreads();
    }
    int loff = sc[tid] - pdeg;
    sl[tid] = loff;
    int node = b * 256 + tid;
    if (node < NN) {
        g_rowptr[node] = padbase + loff;
        g_rowend[node] = padbase + loff + pdeg;
    }
    if (b == NBKT - 1 && tid == 0) g_rowptr[NN] = NEDGE;
    __syncthreads();
    for (int i = tid; i < cntE; i += 256) {
        int p = (i < DCAP) ? stg[i] : g_bin[base + i];
        int dl = p & 255;
        int k2 = (dl << 2) | (p >> 23);
        int rk = atomicAdd(&c2[k2], 1);
        g_csr[padbase + sl[dl] + sgb[k2] + rk] = p >> 8;
    }
    // fill pad slots with sentinel
    if (node < NN) {
        for (int k = deg; k < pdeg; ++k)
            g_csr[padbase + loff + k] = NN;
    }
}

// ---------------- init layer 0: PA = x*Wi0 + bi0, stats ----------------
__global__ void k_init0_v17(const float* __restrict__ x, const float* __restrict__ Wi0,
                            const float* __restrict__ bi0)
{
    int j = threadIdx.x & 31, ns = threadIdx.x >> 5;
    float w = Wi0[j];
    float bb = bi0[j];
    __shared__ float red[64];
    if (threadIdx.x < 64) red[threadIdx.x] = 0.f;
    __syncthreads();
    float s1 = 0.f, s2 = 0.f;
    for (int t = blockIdx.x; t < NN / 8; t += gridDim.x) {
        int n = t * 8 + ns;
        float v = x[n] * w + bb;
        gA[OFF_PA + n * 32 + j] = v;
        s1 += v; s2 += v * v;
    }
    atomicAdd(&red[j], s1);
    atomicAdd(&red[j + 32], s2);
    __syncthreads();
    if (threadIdx.x < 64)
        atomicAdd(&gA[OFF_STATS + (blockIdx.x & (STC - 1)) * 64 + threadIdx.x], red[threadIdx.x]);
}

// ------- BN+LReLU (+resid) (+feats) (+fused 32x32 linear + stats), 32-node tiles -------
__global__ __launch_bounds__(256) void k_nl_v24(int off_in, int off_out, int out_msg, int st_in,
                         const float* __restrict__ gamma, const float* __restrict__ beta,
                         int off_resid, int off_feats,
                         const float* __restrict__ Wn, const float* __restrict__ bn,
                         int st_out)
{
    int tid = threadIdx.x;
    int j = tid & 31, grp = tid >> 5;
    __shared__ float sstat[64];
    __shared__ float red[64];
    __shared__ float sH[32][32];
    if (tid < 64) {
        red[tid] = 0.f;
        float acc = 0.f;
        int base = st_in + tid;
        #pragma unroll 8
        for (int c = 0; c < STC; ++c) acc += gA[base + c * 64];
        sstat[tid] = acc;
    }
    __syncthreads();
    float mean = sstat[j] * (1.f / NN);
    float var  = sstat[32 + j] * (1.f / NN) - mean * mean;
    float scale = gamma[j] * rsqrtf(var + EPS);
    float shift = beta[j] - mean * scale;

    float wc[32]; float bb = 0.f;
    if (Wn) {
        #pragma unroll
        for (int k = 0; k < 32; ++k) wc[k] = Wn[k * 32 + j];
        bb = bn[j];
    }
    unsigned short* mb = (unsigned short*)(gA + OFF_MSGB);
    float s1 = 0.f, s2 = 0.f;
    for (int t = blockIdx.x; t < NTILE; t += gridDim.x) {
        int base = t * 1024;
        #pragma unroll
        for (int k = 0; k < 4; ++k) {
            int idx = tid + 256 * k;
            float v = gA[off_in + base + idx];
            v = lrelu(scale * v + shift);
            if (off_resid >= 0) v += gA[off_resid + base + idx];
            if (off_feats >= 0) gA[off_feats + base + idx] = v;
            ((float*)sH)[idx] = v;
        }
        if (Wn) {
            __syncthreads();
            #pragma unroll
            for (int q = 0; q < 4; ++q) {
                int nl = grp * 4 + q;
                float acc = bb;
                #pragma unroll
                for (int k = 0; k < 32; k += 4) {
                    float4 h4 = *(const float4*)&sH[nl][k];
                    acc += h4.x * wc[k] + h4.y * wc[k + 1] + h4.z * wc[k + 2] + h4.w * wc[k + 3];
                }
                int n = t * 32 + nl;
                if (out_msg) mb[n * 32 + j] = f2b(acc);
                else gA[off_out + n * 32 + j] = acc;
                s1 += acc; s2 += acc * acc;
            }
            __syncthreads();
        }
    }
    if (Wn) {
        atomicAdd(&red[j], s1);
        atomicAdd(&red[j + 32], s2);
        __syncthreads();
        if (tid < 64)
            atomicAdd(&gA[st_out + (blockIdx.x & (STC - 1)) * 64 + tid], red[tid]);
    }
}

// ---- per-node post-activation: TACT = bf16(lrelu(BN(MSGB))) [node][32]; row NN stays zero ----
__global__ __launch_bounds__(256) void k_act_v21(int st_msg,
                                                 const float* __restrict__ gm,
                                                 const float* __restrict__ bem)
{
    __shared__ float sstat[64];
    __shared__ float scl[32], shf[32];
    int tid = threadIdx.x;
    if (tid < 64) {
        float acc = 0.f;
        int base = st_msg + tid;
        #pragma unroll 8
        for (int c = 0; c < STC; ++c) acc += gA[base + c * 64];
        sstat[tid] = acc;
    }
    __syncthreads();
    if (tid < 32) {
        float mean = sstat[tid] * (1.f / NN);
        float var  = sstat[32 + tid] * (1.f / NN) - mean * mean;
        float s = gm[tid] * rsqrtf(var + EPS);
        scl[tid] = s;
        shf[tid] = bem[tid] - mean * s;
    }
    __syncthreads();
    int idx = blockIdx.x * 256 + tid;          // uint4 index over NV/8
    if (idx >= NV / 8) return;
    const uint4* src = (const uint4*)(gA + OFF_MSGB);
    uint4* dst = (uint4*)(gA + OFF_TACT);
    uint4 m = src[idx];
    int fb = (idx & 3) * 8;
    uint4 o;
    #pragma unroll
    for (int w = 0; w < 4; ++w) {
        unsigned int u = (&m.x)[w];
        int f0 = fb + 2 * w;
        float vlo = lrelu(scl[f0]     * __uint_as_float(u << 16)         + shf[f0]);
        float vhi = lrelu(scl[f0 + 1] * __uint_as_float(u & 0xffff0000u) + shf[f0 + 1]);
        (&o.x)[w] = (unsigned int)f2b(vlo) | ((unsigned int)f2b(vhi) << 16);
    }
    dst[idx] = o;
}

// ======== fused gather + update GEMM: 1-wave blocks (16 nodes) ========
// No cross-wave barrier: A->B sync is wave-internal (lockstep). Finished blocks
// retire immediately -> degree imbalance no longer holds 4 waves hostage.
// Same padded-row int4-index inner loop as v27.
#define ACC8(mm) { \
    unsigned int u_; \
    u_ = (mm).x; a[0] += __uint_as_float(u_ << 16); a[1] += __uint_as_float(u_ & 0xffff0000u); \
    u_ = (mm).y; a[2] += __uint_as_float(u_ << 16); a[3] += __uint_as_float(u_ & 0xffff0000u); \
    u_ = (mm).z; a[4] += __uint_as_float(u_ << 16); a[5] += __uint_as_float(u_ & 0xffff0000u); \
    u_ = (mm).w; a[6] += __uint_as_float(u_ << 16); a[7] += __uint_as_float(u_ & 0xffff0000u); }

__global__ __launch_bounds__(64) void k_gupd_v28(int off_h,
                                                 const float* __restrict__ Wu_i,
                                                 const float* __restrict__ bu_i,
                                                 int st_out)
{
    __shared__ float sH[16][36];
    __shared__ float sAgg[16][36];
    __shared__ float red[64];
    int tid = threadIdx.x;
    int nb = blockIdx.x * 16;

    red[tid] = 0.f;
    {
        const float* hp = gA + off_h + nb * 32;
        int lim = min(512, (NN - nb) * 32);
        for (int idx = tid; idx < lim; idx += 64)
            sH[idx >> 5][idx & 31] = hp[idx];
    }

    // ---- phase A: gather (padded rows) ----
    {
        int nl = tid >> 2;          // local node 0..15
        int g  = tid & 3;           // feature group (8 feats)
        int n  = nb + nl;
        float a[8];
        #pragma unroll
        for (int q = 0; q < 8; ++q) a[q] = 0.f;
        if (n < NN) {
            const unsigned short* tb = (const unsigned short*)(gA + OFF_TACT);
            int e = g_rowptr[n], e1 = g_rowend[n];   // (e1-e)%4==0, e 16B-aligned
            for (; e + 7 < e1; e += 8) {
                int4 c0 = *(const int4*)(g_csr + e);
                int4 c1 = *(const int4*)(g_csr + e + 4);
                uint4 m0 = *(const uint4*)(tb + (c0.x << 5) + (g << 3));
                uint4 m1 = *(const uint4*)(tb + (c0.y << 5) + (g << 3));
                uint4 m2 = *(const uint4*)(tb + (c0.z << 5) + (g << 3));
                uint4 m3 = *(const uint4*)(tb + (c0.w << 5) + (g << 3));
                uint4 m4 = *(const uint4*)(tb + (c1.x << 5) + (g << 3));
                uint4 m5 = *(const uint4*)(tb + (c1.y << 5) + (g << 3));
                uint4 m6 = *(const uint4*)(tb + (c1.z << 5) + (g << 3));
                uint4 m7 = *(const uint4*)(tb + (c1.w << 5) + (g << 3));
                ACC8(m0) ACC8(m1) ACC8(m2) ACC8(m3)
                ACC8(m4) ACC8(m5) ACC8(m6) ACC8(m7)
            }
            if (e < e1) {                            // exactly 4 remain
                int4 c0 = *(const int4*)(g_csr + e);
                uint4 m0 = *(const uint4*)(tb + (c0.x << 5) + (g << 3));
                uint4 m1 = *(const uint4*)(tb + (c0.y << 5) + (g << 3));
                uint4 m2 = *(const uint4*)(tb + (c0.z << 5) + (g << 3));
                uint4 m3 = *(const uint4*)(tb + (c0.w << 5) + (g << 3));
                ACC8(m0) ACC8(m1) ACC8(m2) ACC8(m3)
            }
        }
        *(float4*)&sAgg[nl][g * 8]     = make_float4(a[0], a[1], a[2], a[3]);
        *(float4*)&sAgg[nl][g * 8 + 4] = make_float4(a[4], a[5], a[6], a[7]);
    }
    __syncthreads();   // single-wave block: compiles to lgkm wait, no cross-wave stall

    // ---- phase B: update GEMM (16 nodes, 2 rows/iter) ----
    {
        int j = tid & 31, ns = tid >> 5;
        float wc[64];
        #pragma unroll
        for (int k = 0; k < 64; ++k) wc[k] = Wu_i[k * 32 + j];
        float bb = bu_i[j];
        float s1 = 0.f, s2 = 0.f;
        #pragma unroll
        for (int it = 0; it < 8; ++it) {
            int nl = it * 2 + ns;
            int n = nb + nl;
            if (n >= NN) break;
            float acc = bb;
            #pragma unroll
            for (int k = 0; k < 32; k += 4) {
                float4 h4 = *(const float4*)&sH[nl][k];
                acc += h4.x * wc[k] + h4.y * wc[k + 1] + h4.z * wc[k + 2] + h4.w * wc[k + 3];
                float4 a4 = *(const float4*)&sAgg[nl][k];
                acc += a4.x * wc[32 + k] + a4.y * wc[32 + k + 1] + a4.z * wc[32 + k + 2] + a4.w * wc[32 + k + 3];
            }
            gA[OFF_PB + n * 32 + j] = acc;
            s1 += acc; s2 += acc * acc;
        }
        atomicAdd(&red[j], s1);
        atomicAdd(&red[j + 32], s2);
        __syncthreads();
        atomicAdd(&gA[st_out + (blockIdx.x & (STC - 1)) * 64 + tid], red[tid]);
    }
}

// ================= MFMA final MLP =================
typedef __attribute__((ext_vector_type(8))) short bf16x8;
typedef __attribute__((ext_vector_type(4))) float f32x4;

union FC { uint4 u; bf16x8 b; };

#define MFMA(a, b, c) __builtin_amdgcn_mfma_f32_16x16x32_bf16(a, b, c, 0, 0, 0)

__device__ __forceinline__ bf16x8 ld_wf(const uint4* p) {
    FC c; c.u = *p; return c.b;
}

__device__ __forceinline__ f32x4 ld_bias4(const float* p) {
    float4 t = *(const float4*)p;
    f32x4 r; r[0] = t.x; r[1] = t.y; r[2] = t.z; r[3] = t.w; return r;
}

__device__ __forceinline__ f32x4 lrelu4(f32x4 v) {
    f32x4 r;
    #pragma unroll
    for (int k = 0; k < 4; ++k) r[k] = v[k] > 0.f ? v[k] : v[k] * NEG;
    return r;
}

__device__ __forceinline__ void splitpack(const float* v, bf16x8& hi, bf16x8& lo) {
    unsigned int h[4], l[4];
    #pragma unroll
    for (int k = 0; k < 4; ++k) {
        unsigned short h0 = f2b(v[2*k]), h1 = f2b(v[2*k+1]);
        float r0 = v[2*k]   - b2f(h0);
        float r1 = v[2*k+1] - b2f(h1);
        h[k] = (unsigned int)h0 | ((unsigned int)h1 << 16);
        l[k] = (unsigned int)f2b(r0) | ((unsigned int)f2b(r1) << 16);
    }
    FC ch; ch.u = make_uint4(h[0], h[1], h[2], h[3]); hi = ch.b;
    FC cl; cl.u = make_uint4(l[0], l[1], l[2], l[3]); lo = cl.b;
}

__global__ __launch_bounds__(256) void k_wprep_v18(const float* __restrict__ W0,
                                                   const float* __restrict__ W1,
                                                   const float* __restrict__ W2,
                                                   const float* __restrict__ W3)
{
    int i = blockIdx.x * 256 + threadIdx.x;
    if (i >= 51200) return;
    const float* src; int Nout, nk; int r = i;
    if (r < 8192)       { src = W0; Nout = 256; nk = 1; }
    else if (r < 40960) { src = W1; Nout = 128; nk = 8; r -= 8192; }
    else if (r < 49152) { src = W2; Nout = 64;  nk = 4; r -= 40960; }
    else                { src = W3; Nout = 32;  nk = 2; r -= 49152; }
    int frag = r >> 9;
    int lane = (r >> 3) & 63;
    int j = r & 7;
    int T = frag / nk, s = frag - T * nk;
    int g = lane >> 4;
    int outf = T * 16 + (lane & 15);
    int inf = 32 * s + 16 * (j >> 2) + 4 * g + (j & 3);
    unsigned short* dst = (unsigned short*)(gA + OFF_WF);
    dst[i] = f2b(src[inf * Nout + outf]);
}

__global__ __launch_bounds__(256) void k_final_v18(
    int off_h,
    const float* __restrict__ bf0, const float* __restrict__ bf1,
    const float* __restrict__ bf2, const float* __restrict__ bf3,
    const float* __restrict__ Wo,  const float* __restrict__ bo,
    float* __restrict__ out)
{
    int lane = threadIdx.x & 63;
    int wave = threadIdx.x >> 6;
    int c = lane & 15;
    int g = lane >> 4;
    int nb = blockIdx.x * 128 + wave * 32;
    int n0 = nb + c;
    int n1 = nb + 16 + c;
    int ld0 = min(n0, NN - 1), ld1 = min(n1, NN - 1);

    const float* h = gA + off_h;
    const uint4* WF = (const uint4*)(gA + OFF_WF);

    float4 ia0 = *(const float4*)&h[ld0 * 32 + 4 * g];
    float4 ib0 = *(const float4*)&h[ld0 * 32 + 16 + 4 * g];
    float4 ia1 = *(const float4*)&h[ld1 * 32 + 4 * g];
    float4 ib1 = *(const float4*)&h[ld1 * 32 + 16 + 4 * g];
    bf16x8 Bh0, Bl0, Bh1, Bl1;
    {
        float v0[8] = {ia0.x, ia0.y, ia0.z, ia0.w, ib0.x, ib0.y, ib0.z, ib0.w};
        float v1[8] = {ia1.x, ia1.y, ia1.z, ia1.w, ib1.x, ib1.y, ib1.z, ib1.w};
        splitpack(v0, Bh0, Bl0);
        splitpack(v1, Bh1, Bl1);
    }

    f32x4 A0[16][2];
    #pragma unroll
    for (int t = 0; t < 16; ++t) {
        f32x4 ci = ld_bias4(bf0 + t * 16 + 4 * g);
        bf16x8 w = ld_wf(WF + W0B + t * 64 + lane);
        f32x4 d0 = MFMA(w, Bh0, ci);
        d0 = MFMA(w, Bl0, d0);
        f32x4 d1 = MFMA(w, Bh1, ci);
        d1 = MFMA(w, Bl1, d1);
        A0[t][0] = lrelu4(d0);
        A0[t][1] = lrelu4(d1);
    }

    f32x4 A1[8][2];
    #pragma unroll
    for (int T = 0; T < 8; ++T) {
        f32x4 ci = ld_bias4(bf1 + T * 16 + 4 * g);
        A1[T][0] = ci; A1[T][1] = ci;
    }
    #pragma unroll
    for (int s = 0; s < 8; ++s) {
        bf16x8 bh[2], bl[2];
        #pragma unroll
        for (int u = 0; u < 2; ++u) {
            float vv[8] = {A0[2*s][u][0], A0[2*s][u][1], A0[2*s][u][2], A0[2*s][u][3],
                           A0[2*s+1][u][0], A0[2*s+1][u][1], A0[2*s+1][u][2], A0[2*s+1][u][3]};
            splitpack(vv, bh[u], bl[u]);
        }
        #pragma unroll
        for (int T = 0; T < 8; ++T) {
            bf16x8 w = ld_wf(WF + W1B + (T * 8 + s) * 64 + lane);
            A1[T][0] = MFMA(w, bh[0], A1[T][0]);
            A1[T][0] = MFMA(w, bl[0], A1[T][0]);
            A1[T][1] = MFMA(w, bh[1], A1[T][1]);
            A1[T][1] = MFMA(w, bl[1], A1[T][1]);
        }
    }
    #pragma unroll
    for (int T = 0; T < 8; ++T) { A1[T][0] = lrelu4(A1[T][0]); A1[T][1] = lrelu4(A1[T][1]); }

    f32x4 A2[4][2];
    #pragma unroll
    for (int T = 0; T < 4; ++T) {
        f32x4 ci = ld_bias4(bf2 + T * 16 + 4 * g);
        A2[T][0] = ci; A2[T][1] = ci;
    }
    #pragma unroll
    for (int s = 0; s < 4; ++s) {
        bf16x8 bh[2], bl[2];
        #pragma unroll
        for (int u = 0; u < 2; ++u) {
            float vv[8] = {A1[2*s][u][0], A1[2*s][u][1], A1[2*s][u][2], A1[2*s][u][3],
                           A1[2*s+1][u][0], A1[2*s+1][u][1], A1[2*s+1][u][2], A1[2*s+1][u][3]};
            splitpack(vv, bh[u], bl[u]);
        }
        #pragma unroll
        for (int T = 0; T < 4; ++T) {
            bf16x8 w = ld_wf(WF + W2B + (T * 4 + s) * 64 + lane);
            A2[T][0] = MFMA(w, bh[0], A2[T][0]);
            A2[T][0] = MFMA(w, bl[0], A2[T][0]);
            A2[T][1] = MFMA(w, bh[1], A2[T][1]);
            A2[T][1] = MFMA(w, bl[1], A2[T][1]);
        }
    }
    #pragma unroll
    for (int T = 0; T < 4; ++T) { A2[T][0] = lrelu4(A2[T][0]); A2[T][1] = lrelu4(A2[T][1]); }

    f32x4 A3[2][2];
    #pragma unroll
    for (int T = 0; T < 2; ++T) {
        f32x4 ci = ld_bias4(bf3 + T * 16 + 4 * g);
        A3[T][0] = ci; A3[T][1] = ci;
    }
    #pragma unroll
    for (int s = 0; s < 2; ++s) {
        bf16x8 bh[2], bl[2];
        #pragma unroll
        for (int u = 0; u < 2; ++u) {
            float vv[8] = {A2[2*s][u][0], A2[2*s][u][1], A2[2*s][u][2], A2[2*s][u][3],
                           A2[2*s+1][u][0], A2[2*s+1][u][1], A2[2*s+1][u][2], A2[2*s+1][u][3]};
            splitpack(vv, bh[u], bl[u]);
        }
        #pragma unroll
        for (int T = 0; T < 2; ++T) {
            bf16x8 w = ld_wf(WF + W3B + (T * 2 + s) * 64 + lane);
            A3[T][0] = MFMA(w, bh[0], A3[T][0]);
            A3[T][0] = MFMA(w, bl[0], A3[T][0]);
            A3[T][1] = MFMA(w, bh[1], A3[T][1]);
            A3[T][1] = MFMA(w, bl[1], A3[T][1]);
        }
    }
    #pragma unroll
    for (int T = 0; T < 2; ++T) { A3[T][0] = lrelu4(A3[T][0]); A3[T][1] = lrelu4(A3[T][1]); }

    float4 woa = *(const float4*)&Wo[4 * g];
    float4 wob = *(const float4*)&Wo[16 + 4 * g];
    float z0 = A3[0][0][0]*woa.x + A3[0][0][1]*woa.y + A3[0][0][2]*woa.z + A3[0][0][3]*woa.w
             + A3[1][0][0]*wob.x + A3[1][0][1]*wob.y + A3[1][0][2]*wob.z + A3[1][0][3]*wob.w;
    float z1 = A3[0][1][0]*woa.x + A3[0][1][1]*woa.y + A3[0][1][2]*woa.z + A3[0][1][3]*woa.w
             + A3[1][1][0]*wob.x + A3[1][1][1]*wob.y + A3[1][1][2]*wob.z + A3[1][1][3]*wob.w;
    z0 += __shfl_xor(z0, 16); z0 += __shfl_xor(z0, 32);
    z1 += __shfl_xor(z1, 16); z1 += __shfl_xor(z1, 32);
    float bb = bo[0];
    if (g == 0 && n0 < NN) out[n0] = 1.f / (1.f + __expf(-(z0 + bb)));
    if (g == 1 && n1 < NN) out[n1] = 1.f / (1.f + __expf(-(z1 + bb)));
}

extern "C" void kernel_launch(void* const* d_in, const int* in_sizes, int n_in,
                              void* d_out, int out_size, void* d_ws, size_t ws_size,
                              hipStream_t stream)
{
    (void)in_sizes; (void)n_in; (void)out_size; (void)d_ws; (void)ws_size;
    float* out = (float*)d_out;

    const float* x   = (const float*)d_in[0];
    const int*  col  = (const int*) d_in[1];
    const float* Wi0 = (const float*)d_in[2];
    const float* bi0 = (const float*)d_in[3];
    const float* gi0 = (const float*)d_in[4];
    const float* bei0= (const float*)d_in[5];
    const float* Wi1 = (const float*)d_in[6];
    const float* bi1 = (const float*)d_in[7];
    const float* gi1 = (const float*)d_in[8];
    const float* bei1= (const float*)d_in[9];
    const float* Wm  = (const float*)d_in[10];
    const float* bm  = (const float*)d_in[11];
    const float* gm  = (const float*)d_in[12];
    const float* bem = (const float*)d_in[13];
    const float* Wu  = (const float*)d_in[14];
    const float* bu  = (const float*)d_in[15];
    const float* gu  = (const float*)d_in[16];
    const float* beu = (const float*)d_in[17];
    const float* Wf0 = (const float*)d_in[18];
    const float* bf0 = (const float*)d_in[19];
    const float* Wf1 = (const float*)d_in[20];
    const float* bf1 = (const float*)d_in[21];
    const float* Wf2 = (const float*)d_in[22];
    const float* bf2 = (const float*)d_in[23];
    const float* Wf3 = (const float*)d_in[24];
    const float* bf3 = (const float*)d_in[25];
    const float* Wo  = (const float*)d_in[26];
    const float* bo  = (const float*)d_in[27];

    const int st_i0 = OFF_STATS;
    const int st_i1 = OFF_STATS + ST_STRIDE;
    const int st_m  = OFF_STATS + 2 * ST_STRIDE;    // + i*ST_STRIDE
    const int st_u  = OFF_STATS + 12 * ST_STRIDE;   // + i*ST_STRIDE

    const int RING[4] = { OFF_RING, OFF_RING + NV, OFF_RING + 2 * NV, OFF_RING + 3 * NV };

    dim3 blk(256);
    k_zero_v19<<<NBLK, blk, 0, stream>>>();
    k_bcnt_v19<<<NCBLK, blk, 0, stream>>>(col);
    k_bscan_v19<<<1, 512, 0, stream>>>();
    k_binfill_v19<<<NCBLK, blk, 0, stream>>>(col);
    k_csr_v27<<<NBKT, blk, 0, stream>>>();
    k_wprep_v18<<<200, blk, 0, stream>>>(Wf0, Wf1, Wf2, Wf3);

    // init MLP: x -> h0 (ring[0]); last k_nl chains layer-0 msg linear into bf16 MSGB
    k_init0_v17<<<1024, blk, 0, stream>>>(x, Wi0, bi0);
    k_nl_v24<<<782, blk, 0, stream>>>(OFF_PA, OFF_PB, 0, st_i0, gi0, bei0, -1, -1, Wi1, bi1, st_i1);
    k_nl_v24<<<782, blk, 0, stream>>>(OFF_PB, 0, 1, st_i1, gi1, bei1, -1, RING[0], Wm, bm, st_m);

    for (int i = 0; i < 10; ++i) {
        int h_cur = RING[i & 3];
        int h_new = RING[(i + 1) & 3];
        int resid = (i >= 2) ? RING[(i - 2) & 3] : -1;
        k_act_v21<<<1563, blk, 0, stream>>>(st_m + i * ST_STRIDE, gm + i * 32, bem + i * 32);
        k_gupd_v28<<<NGBLK, dim3(64), 0, stream>>>(h_cur, Wu + i * 2048, bu + i * 32,
                                                   st_u + i * ST_STRIDE);
        const float* Wn = (i < 9) ? (Wm + (i + 1) * 1024) : nullptr;
        const float* bn = (i < 9) ? (bm + (i + 1) * 32) : nullptr;
        int st_next = (i < 9) ? (st_m + (i + 1) * ST_STRIDE) : 0;
        k_nl_v24<<<782, blk, 0, stream>>>(OFF_PB, 0, 1, st_u + i * ST_STRIDE,
                                          gu + i * 32, beu + i * 32,
                                          resid, h_new, Wn, bn, st_next);
    }

    k_final_v18<<<782, blk, 0, stream>>>(RING[2], bf0, bf1, bf2, bf3, Wo, bo, out);
}

// Round 14
// 871.039 us; speedup vs baseline: 1.2184x; 1.0340x over previous
//
#include <hip/hip_runtime.h>
#include <hip/hip_bf16.h>

#define NN 100000
#define NEDGE 1600000
#define NV (NN*32)
#define NEG 0.01f
#define EPS 1e-5f
#define NBLK 391            // ceil(NN/256)
#define NBKT 391            // node buckets (256 nodes each)
#define CHUNK 4096          // edges per binning block
#define NCBLK 391           // ceil(NEDGE/CHUNK)
#define DCAP 6144           // LDS stage capacity in k_csr (mean 4096 + 32 sigma)
#define STC 64              // stat copies (contention spread)
#define ST_STRIDE 4096      // STC * 64
#define NGBLK 6250          // ceil(NN/16) 1-wave gather blocks
#define NT8 12500           // NN/8 tiles for 1-wave k_nl
#define CSRX (NEDGE + 302080)  // padded CSR capacity (align4 + 772/bucket)

// ---- static device arena (fp32) ----
#define OFF_STATS 0
#define STATS_F  (22*ST_STRIDE)
#define OFF_PA   STATS_F
#define OFF_PB   (OFF_PA + NV)
#define OFF_TACT (OFF_PB + NV)           // post-act bf16 msgs (rows 0..NN; row NN stays zero = sentinel)
#define OFF_MSGB (OFF_TACT + NV)         // pre-act bf16 msgs
#define OFF_RING (OFF_MSGB + NV/2)
#define OFF_WF   (OFF_RING + 4*NV)       // bf16 weight frags for final MLP (51200 shorts)
#define ARENA_F  (OFF_WF + 25600)

// weight-frag section bases in uint4 (16B) units
#define W0B 0
#define W1B 1024
#define W2B 5120
#define W3B 6144

__device__ __align__(16) float gA[ARENA_F];
__device__ int g_rowptr[NN + 1];
__device__ int g_rowend[NN];        // padded row end (start + pdeg)
__device__ __align__(16) int g_csr[CSRX];
__device__ int g_bin[NEDGE];       // bucket-grouped packed edges: (src<<8)|dlocal
__device__ int g_bcnt[NBKT];
__device__ int g_boff[NBKT];
__device__ int g_btail[NBKT];

__device__ __forceinline__ float lrelu(float v) { return v > 0.f ? v : v * NEG; }
__device__ __forceinline__ unsigned short f2b(float v) {
    __hip_bfloat16 b = __float2bfloat16(v);
    return *reinterpret_cast<unsigned short*>(&b);
}
__device__ __forceinline__ float b2f(unsigned short u) {
    __hip_bfloat16 b = *reinterpret_cast<__hip_bfloat16*>(&u);
    return __bfloat162float(b);
}

// ---------------- zero stats + bucket counts ----------------
__global__ void k_zero_v19()
{
    int i = blockIdx.x * 256 + threadIdx.x;
    if (i < STATS_F) gA[i] = 0.f;
    if (i < NBKT) g_bcnt[i] = 0;
}

// ---------------- bucket histogram (LDS-staged, low-contention) ----------------
__global__ __launch_bounds__(256) void k_bcnt_v19(const int* __restrict__ col)
{
    __shared__ int hist[NBKT];
    int tid = threadIdx.x;
    for (int b = tid; b < NBKT; b += 256) hist[b] = 0;
    __syncthreads();
    int e0 = blockIdx.x * CHUNK;
    #pragma unroll
    for (int r = 0; r < CHUNK / 256; ++r) {
        int e = e0 + r * 256 + tid;
        if (e < NEDGE) atomicAdd(&hist[col[NEDGE + e] >> 8], 1);
    }
    __syncthreads();
    for (int b = tid; b < NBKT; b += 256) {
        int v = hist[b];
        if (v) atomicAdd(&g_bcnt[b], v);
    }
}

// ---------------- scan bucket counts -> offsets + tails ----------------
__global__ __launch_bounds__(512) void k_bscan_v19()
{
    __shared__ int s[512];
    int t = threadIdx.x;
    int v = (t < NBKT) ? g_bcnt[t] : 0;
    s[t] = v;
    __syncthreads();
    for (int off = 1; off < 512; off <<= 1) {
        int u = (t >= off) ? s[t - off] : 0;
        __syncthreads();
        s[t] += u;
        __syncthreads();
    }
    if (t < NBKT) {
        int o = s[t] - v;
        g_boff[t] = o;
        g_btail[t] = o;
    }
}

// ---------------- bin edges into bucket-contiguous regions (chunked append) ----------------
__global__ __launch_bounds__(256) void k_binfill_v19(const int* __restrict__ col)
{
    __shared__ int ssrc[CHUNK];
    __shared__ int sdst[CHUNK];
    __shared__ int hist[NBKT];
    __shared__ int boffL[NBKT];
    __shared__ int cnt2[NBKT];
    int tid = threadIdx.x;
    for (int b = tid; b < NBKT; b += 256) { hist[b] = 0; cnt2[b] = 0; }
    __syncthreads();
    int e0 = blockIdx.x * CHUNK;
    #pragma unroll
    for (int r = 0; r < CHUNK / 256; ++r) {
        int i = r * 256 + tid;
        int e = e0 + i;
        if (e < NEDGE) {
            int s = col[e];
            int d = col[NEDGE + e];
            ssrc[i] = s;
            sdst[i] = d;
            atomicAdd(&hist[d >> 8], 1);
        }
    }
    __syncthreads();
    for (int b = tid; b < NBKT; b += 256) {
        int h = hist[b];
        if (h) boffL[b] = atomicAdd(&g_btail[b], h);
    }
    __syncthreads();
    #pragma unroll
    for (int r = 0; r < CHUNK / 256; ++r) {
        int i = r * 256 + tid;
        int e = e0 + i;
        if (e < NEDGE) {
            int d = sdst[i];
            int b = d >> 8;
            int rk = atomicAdd(&cnt2[b], 1);
            g_bin[boffL[b] + rk] = (ssrc[i] << 8) | (d & 255);
        }
    }
}

// ------- per-bucket counting scatter -> PADDED CSR (rows 16B-aligned, len%4==0) -------
// Pad slots hold sentinel src=NN (zero TACT row) -> gather needs no remainder loop.
__global__ __launch_bounds__(256) void k_csr_v27()
{
    __shared__ int stg[DCAP];
    __shared__ int c1[1024];     // [dlocal][seg] counts
    __shared__ int sgb[1024];    // [dlocal][seg] start within row
    __shared__ int c2[1024];     // scatter ranks
    __shared__ int sc[256];
    __shared__ int sl[256];
    int tid = threadIdx.x, b = blockIdx.x;
    int base = g_boff[b];
    int cntE = g_bcnt[b];
    int padbase = ((base + 3) & ~3) + 772 * b;
    #pragma unroll
    for (int k = 0; k < 4; ++k) { c1[tid + 256 * k] = 0; c2[tid + 256 * k] = 0; }
    __syncthreads();
    for (int i = tid; i < cntE; i += 256) {
        int p = g_bin[base + i];
        if (i < DCAP) stg[i] = p;
        atomicAdd(&c1[((p & 255) << 2) | (p >> 23)], 1);
    }
    __syncthreads();
    int t0 = c1[tid * 4], t1 = c1[tid * 4 + 1], t2 = c1[tid * 4 + 2], t3 = c1[tid * 4 + 3];
    int deg = t0 + t1 + t2 + t3;
    int pdeg = (deg + 3) & ~3;
    sgb[tid * 4]     = 0;
    sgb[tid * 4 + 1] = t0;
    sgb[tid * 4 + 2] = t0 + t1;
    sgb[tid * 4 + 3] = t0 + t1 + t2;
    sc[tid] = pdeg;
    __syncthreads();
    for (int off = 1; off < 256; off <<= 1) {
        int u = (tid >= off) ? sc[tid - off] : 0;
        __syncthreads();
        sc[tid] += u;
        __syncthreads();
    }
    int loff = sc[tid] - pdeg;
    sl[tid] = loff;
    int node = b * 256 + tid;
    if (node < NN) {
        g_rowptr[node] = padbase + loff;
        g_rowend[node] = padbase + loff + pdeg;
    }
    if (b == NBKT - 1 && tid == 0) g_rowptr[NN] = NEDGE;
    __syncthreads();
    for (int i = tid; i < cntE; i += 256) {
        int p = (i < DCAP) ? stg[i] : g_bin[base + i];
        int dl = p & 255;
        int k2 = (dl << 2) | (p >> 23);
        int rk = atomicAdd(&c2[k2], 1);
        g_csr[padbase + sl[dl] + sgb[k2] + rk] = p >> 8;
    }
    // fill pad slots with sentinel
    if (node < NN) {
        for (int k = deg; k < pdeg; ++k)
            g_csr[padbase + loff + k] = NN;
    }
}

// ---------------- init layer 0: PA = x*Wi0 + bi0, stats ----------------
__global__ void k_init0_v17(const float* __restrict__ x, const float* __restrict__ Wi0,
                            const float* __restrict__ bi0)
{
    int j = threadIdx.x & 31, ns = threadIdx.x >> 5;
    float w = Wi0[j];
    float bb = bi0[j];
    __shared__ float red[64];
    if (threadIdx.x < 64) red[threadIdx.x] = 0.f;
    __syncthreads();
    float s1 = 0.f, s2 = 0.f;
    for (int t = blockIdx.x; t < NN / 8; t += gridDim.x) {
        int n = t * 8 + ns;
        float v = x[n] * w + bb;
        gA[OFF_PA + n * 32 + j] = v;
        s1 += v; s2 += v * v;
    }
    atomicAdd(&red[j], s1);
    atomicAdd(&red[j + 32], s2);
    __syncthreads();
    if (threadIdx.x < 64)
        atomicAdd(&gA[OFF_STATS + (blockIdx.x & (STC - 1)) * 64 + threadIdx.x], red[threadIdx.x]);
}

// ------- BN+LReLU (+resid) (+feats) (+fused 32x32 linear + stats), 1-WAVE blocks -------
// 8-node tiles, all barriers wave-internal (free), blocks retire immediately.
__global__ __launch_bounds__(64) void k_nl_v29(int off_in, int off_out, int out_msg, int st_in,
                         const float* __restrict__ gamma, const float* __restrict__ beta,
                         int off_resid, int off_feats,
                         const float* __restrict__ Wn, const float* __restrict__ bn,
                         int st_out)
{
    int tid = threadIdx.x;
    int j = tid & 31, ns = tid >> 5;    // ns in 0..1
    __shared__ float sstat[64];
    __shared__ float red[64];
    __shared__ float sH[8][32];
    red[tid] = 0.f;
    {
        float acc = 0.f;
        int base = st_in + tid;
        #pragma unroll 8
        for (int c = 0; c < STC; ++c) acc += gA[base + c * 64];
        sstat[tid] = acc;
    }
    __syncthreads();
    float mean = sstat[j] * (1.f / NN);
    float var  = sstat[32 + j] * (1.f / NN) - mean * mean;
    float scale = gamma[j] * rsqrtf(var + EPS);
    float shift = beta[j] - mean * scale;

    float wc[32]; float bb = 0.f;
    if (Wn) {
        #pragma unroll
        for (int k = 0; k < 32; ++k) wc[k] = Wn[k * 32 + j];
        bb = bn[j];
    }
    unsigned short* mb = (unsigned short*)(gA + OFF_MSGB);
    float s1 = 0.f, s2 = 0.f;
    for (int t = blockIdx.x; t < NT8; t += gridDim.x) {
        int base = t * 256;
        #pragma unroll
        for (int k = 0; k < 4; ++k) {
            int idx = tid + 64 * k;      // (idx&31)==j since 64%32==0
            float v = gA[off_in + base + idx];
            v = lrelu(scale * v + shift);
            if (off_resid >= 0) v += gA[off_resid + base + idx];
            if (off_feats >= 0) gA[off_feats + base + idx] = v;
            ((float*)sH)[idx] = v;
        }
        if (Wn) {
            __syncthreads();             // 1-wave: near-free
            #pragma unroll
            for (int q = 0; q < 4; ++q) {
                int nl = q * 2 + ns;
                float acc = bb;
                #pragma unroll
                for (int k = 0; k < 32; k += 4) {
                    float4 h4 = *(const float4*)&sH[nl][k];
                    acc += h4.x * wc[k] + h4.y * wc[k + 1] + h4.z * wc[k + 2] + h4.w * wc[k + 3];
                }
                int n = t * 8 + nl;
                if (out_msg) mb[n * 32 + j] = f2b(acc);
                else gA[off_out + n * 32 + j] = acc;
                s1 += acc; s2 += acc * acc;
            }
            __syncthreads();
        }
    }
    if (Wn) {
        atomicAdd(&red[j], s1);
        atomicAdd(&red[j + 32], s2);
        __syncthreads();
        atomicAdd(&gA[st_out + (blockIdx.x & (STC - 1)) * 64 + tid], red[tid]);
    }
}

// ---- per-node post-activation: TACT = bf16(lrelu(BN(MSGB))) [node][32]; row NN stays zero ----
__global__ __launch_bounds__(256) void k_act_v21(int st_msg,
                                                 const float* __restrict__ gm,
                                                 const float* __restrict__ bem)
{
    __shared__ float sstat[64];
    __shared__ float scl[32], shf[32];
    int tid = threadIdx.x;
    if (tid < 64) {
        float acc = 0.f;
        int base = st_msg + tid;
        #pragma unroll 8
        for (int c = 0; c < STC; ++c) acc += gA[base + c * 64];
        sstat[tid] = acc;
    }
    __syncthreads();
    if (tid < 32) {
        float mean = sstat[tid] * (1.f / NN);
        float var  = sstat[32 + tid] * (1.f / NN) - mean * mean;
        float s = gm[tid] * rsqrtf(var + EPS);
        scl[tid] = s;
        shf[tid] = bem[tid] - mean * s;
    }
    __syncthreads();
    int idx = blockIdx.x * 256 + tid;          // uint4 index over NV/8
    if (idx >= NV / 8) return;
    const uint4* src = (const uint4*)(gA + OFF_MSGB);
    uint4* dst = (uint4*)(gA + OFF_TACT);
    uint4 m = src[idx];
    int fb = (idx & 3) * 8;
    uint4 o;
    #pragma unroll
    for (int w = 0; w < 4; ++w) {
        unsigned int u = (&m.x)[w];
        int f0 = fb + 2 * w;
        float vlo = lrelu(scl[f0]     * __uint_as_float(u << 16)         + shf[f0]);
        float vhi = lrelu(scl[f0 + 1] * __uint_as_float(u & 0xffff0000u) + shf[f0 + 1]);
        (&o.x)[w] = (unsigned int)f2b(vlo) | ((unsigned int)f2b(vhi) << 16);
    }
    dst[idx] = o;
}

// ======== fused gather + update GEMM: 1-wave blocks (16 nodes) ========
#define ACC8(mm) { \
    unsigned int u_; \
    u_ = (mm).x; a[0] += __uint_as_float(u_ << 16); a[1] += __uint_as_float(u_ & 0xffff0000u); \
    u_ = (mm).y; a[2] += __uint_as_float(u_ << 16); a[3] += __uint_as_float(u_ & 0xffff0000u); \
    u_ = (mm).z; a[4] += __uint_as_float(u_ << 16); a[5] += __uint_as_float(u_ & 0xffff0000u); \
    u_ = (mm).w; a[6] += __uint_as_float(u_ << 16); a[7] += __uint_as_float(u_ & 0xffff0000u); }

__global__ __launch_bounds__(64) void k_gupd_v28(int off_h,
                                                 const float* __restrict__ Wu_i,
                                                 const float* __restrict__ bu_i,
                                                 int st_out)
{
    __shared__ float sH[16][36];
    __shared__ float sAgg[16][36];
    __shared__ float red[64];
    int tid = threadIdx.x;
    int nb = blockIdx.x * 16;

    red[tid] = 0.f;
    {
        const float* hp = gA + off_h + nb * 32;
        int lim = min(512, (NN - nb) * 32);
        for (int idx = tid; idx < lim; idx += 64)
            sH[idx >> 5][idx & 31] = hp[idx];
    }

    // ---- phase A: gather (padded rows) ----
    {
        int nl = tid >> 2;          // local node 0..15
        int g  = tid & 3;           // feature group (8 feats)
        int n  = nb + nl;
        float a[8];
        #pragma unroll
        for (int q = 0; q < 8; ++q) a[q] = 0.f;
        if (n < NN) {
            const unsigned short* tb = (const unsigned short*)(gA + OFF_TACT);
            int e = g_rowptr[n], e1 = g_rowend[n];   // (e1-e)%4==0, e 16B-aligned
            for (; e + 7 < e1; e += 8) {
                int4 c0 = *(const int4*)(g_csr + e);
                int4 c1 = *(const int4*)(g_csr + e + 4);
                uint4 m0 = *(const uint4*)(tb + (c0.x << 5) + (g << 3));
                uint4 m1 = *(const uint4*)(tb + (c0.y << 5) + (g << 3));
                uint4 m2 = *(const uint4*)(tb + (c0.z << 5) + (g << 3));
                uint4 m3 = *(const uint4*)(tb + (c0.w << 5) + (g << 3));
                uint4 m4 = *(const uint4*)(tb + (c1.x << 5) + (g << 3));
                uint4 m5 = *(const uint4*)(tb + (c1.y << 5) + (g << 3));
                uint4 m6 = *(const uint4*)(tb + (c1.z << 5) + (g << 3));
                uint4 m7 = *(const uint4*)(tb + (c1.w << 5) + (g << 3));
                ACC8(m0) ACC8(m1) ACC8(m2) ACC8(m3)
                ACC8(m4) ACC8(m5) ACC8(m6) ACC8(m7)
            }
            if (e < e1) {                            // exactly 4 remain
                int4 c0 = *(const int4*)(g_csr + e);
                uint4 m0 = *(const uint4*)(tb + (c0.x << 5) + (g << 3));
                uint4 m1 = *(const uint4*)(tb + (c0.y << 5) + (g << 3));
                uint4 m2 = *(const uint4*)(tb + (c0.z << 5) + (g << 3));
                uint4 m3 = *(const uint4*)(tb + (c0.w << 5) + (g << 3));
                ACC8(m0) ACC8(m1) ACC8(m2) ACC8(m3)
            }
        }
        *(float4*)&sAgg[nl][g * 8]     = make_float4(a[0], a[1], a[2], a[3]);
        *(float4*)&sAgg[nl][g * 8 + 4] = make_float4(a[4], a[5], a[6], a[7]);
    }
    __syncthreads();

    // ---- phase B: update GEMM (16 nodes, 2 rows/iter) ----
    {
        int j = tid & 31, ns = tid >> 5;
        float wc[64];
        #pragma unroll
        for (int k = 0; k < 64; ++k) wc[k] = Wu_i[k * 32 + j];
        float bb = bu_i[j];
        float s1 = 0.f, s2 = 0.f;
        #pragma unroll
        for (int it = 0; it < 8; ++it) {
            int nl = it * 2 + ns;
            int n = nb + nl;
            if (n >= NN) break;
            float acc = bb;
            #pragma unroll
            for (int k = 0; k < 32; k += 4) {
                float4 h4 = *(const float4*)&sH[nl][k];
                acc += h4.x * wc[k] + h4.y * wc[k + 1] + h4.z * wc[k + 2] + h4.w * wc[k + 3];
                float4 a4 = *(const float4*)&sAgg[nl][k];
                acc += a4.x * wc[32 + k] + a4.y * wc[32 + k + 1] + a4.z * wc[32 + k + 2] + a4.w * wc[32 + k + 3];
            }
            gA[OFF_PB + n * 32 + j] = acc;
            s1 += acc; s2 += acc * acc;
        }
        atomicAdd(&red[j], s1);
        atomicAdd(&red[j + 32], s2);
        __syncthreads();
        atomicAdd(&gA[st_out + (blockIdx.x & (STC - 1)) * 64 + tid], red[tid]);
    }
}

// ================= MFMA final MLP =================
typedef __attribute__((ext_vector_type(8))) short bf16x8;
typedef __attribute__((ext_vector_type(4))) float f32x4;

union FC { uint4 u; bf16x8 b; };

#define MFMA(a, b, c) __builtin_amdgcn_mfma_f32_16x16x32_bf16(a, b, c, 0, 0, 0)

__device__ __forceinline__ bf16x8 ld_wf(const uint4* p) {
    FC c; c.u = *p; return c.b;
}

__device__ __forceinline__ f32x4 ld_bias4(const float* p) {
    float4 t = *(const float4*)p;
    f32x4 r; r[0] = t.x; r[1] = t.y; r[2] = t.z; r[3] = t.w; return r;
}

__device__ __forceinline__ f32x4 lrelu4(f32x4 v) {
    f32x4 r;
    #pragma unroll
    for (int k = 0; k < 4; ++k) r[k] = v[k] > 0.f ? v[k] : v[k] * NEG;
    return r;
}

__device__ __forceinline__ void splitpack(const float* v, bf16x8& hi, bf16x8& lo) {
    unsigned int h[4], l[4];
    #pragma unroll
    for (int k = 0; k < 4; ++k) {
        unsigned short h0 = f2b(v[2*k]), h1 = f2b(v[2*k+1]);
        float r0 = v[2*k]   - b2f(h0);
        float r1 = v[2*k+1] - b2f(h1);
        h[k] = (unsigned int)h0 | ((unsigned int)h1 << 16);
        l[k] = (unsigned int)f2b(r0) | ((unsigned int)f2b(r1) << 16);
    }
    FC ch; ch.u = make_uint4(h[0], h[1], h[2], h[3]); hi = ch.b;
    FC cl; cl.u = make_uint4(l[0], l[1], l[2], l[3]); lo = cl.b;
}

__global__ __launch_bounds__(256) void k_wprep_v18(const float* __restrict__ W0,
                                                   const float* __restrict__ W1,
                                                   const float* __restrict__ W2,
                                                   const float* __restrict__ W3)
{
    int i = blockIdx.x * 256 + threadIdx.x;
    if (i >= 51200) return;
    const float* src; int Nout, nk; int r = i;
    if (r < 8192)       { src = W0; Nout = 256; nk = 1; }
    else if (r < 40960) { src = W1; Nout = 128; nk = 8; r -= 8192; }
    else if (r < 49152) { src = W2; Nout = 64;  nk = 4; r -= 40960; }
    else                { src = W3; Nout = 32;  nk = 2; r -= 49152; }
    int frag = r >> 9;
    int lane = (r >> 3) & 63;
    int j = r & 7;
    int T = frag / nk, s = frag - T * nk;
    int g = lane >> 4;
    int outf = T * 16 + (lane & 15);
    int inf = 32 * s + 16 * (j >> 2) + 4 * g + (j & 3);
    unsigned short* dst = (unsigned short*)(gA + OFF_WF);
    dst[i] = f2b(src[inf * Nout + outf]);
}

__global__ __launch_bounds__(256) void k_final_v18(
    int off_h,
    const float* __restrict__ bf0, const float* __restrict__ bf1,
    const float* __restrict__ bf2, const float* __restrict__ bf3,
    const float* __restrict__ Wo,  const float* __restrict__ bo,
    float* __restrict__ out)
{
    int lane = threadIdx.x & 63;
    int wave = threadIdx.x >> 6;
    int c = lane & 15;
    int g = lane >> 4;
    int nb = blockIdx.x * 128 + wave * 32;
    int n0 = nb + c;
    int n1 = nb + 16 + c;
    int ld0 = min(n0, NN - 1), ld1 = min(n1, NN - 1);

    const float* h = gA + off_h;
    const uint4* WF = (const uint4*)(gA + OFF_WF);

    float4 ia0 = *(const float4*)&h[ld0 * 32 + 4 * g];
    float4 ib0 = *(const float4*)&h[ld0 * 32 + 16 + 4 * g];
    float4 ia1 = *(const float4*)&h[ld1 * 32 + 4 * g];
    float4 ib1 = *(const float4*)&h[ld1 * 32 + 16 + 4 * g];
    bf16x8 Bh0, Bl0, Bh1, Bl1;
    {
        float v0[8] = {ia0.x, ia0.y, ia0.z, ia0.w, ib0.x, ib0.y, ib0.z, ib0.w};
        float v1[8] = {ia1.x, ia1.y, ia1.z, ia1.w, ib1.x, ib1.y, ib1.z, ib1.w};
        splitpack(v0, Bh0, Bl0);
        splitpack(v1, Bh1, Bl1);
    }

    f32x4 A0[16][2];
    #pragma unroll
    for (int t = 0; t < 16; ++t) {
        f32x4 ci = ld_bias4(bf0 + t * 16 + 4 * g);
        bf16x8 w = ld_wf(WF + W0B + t * 64 + lane);
        f32x4 d0 = MFMA(w, Bh0, ci);
        d0 = MFMA(w, Bl0, d0);
        f32x4 d1 = MFMA(w, Bh1, ci);
        d1 = MFMA(w, Bl1, d1);
        A0[t][0] = lrelu4(d0);
        A0[t][1] = lrelu4(d1);
    }

    f32x4 A1[8][2];
    #pragma unroll
    for (int T = 0; T < 8; ++T) {
        f32x4 ci = ld_bias4(bf1 + T * 16 + 4 * g);
        A1[T][0] = ci; A1[T][1] = ci;
    }
    #pragma unroll
    for (int s = 0; s < 8; ++s) {
        bf16x8 bh[2], bl[2];
        #pragma unroll
        for (int u = 0; u < 2; ++u) {
            float vv[8] = {A0[2*s][u][0], A0[2*s][u][1], A0[2*s][u][2], A0[2*s][u][3],
                           A0[2*s+1][u][0], A0[2*s+1][u][1], A0[2*s+1][u][2], A0[2*s+1][u][3]};
            splitpack(vv, bh[u], bl[u]);
        }
        #pragma unroll
        for (int T = 0; T < 8; ++T) {
            bf16x8 w = ld_wf(WF + W1B + (T * 8 + s) * 64 + lane);
            A1[T][0] = MFMA(w, bh[0], A1[T][0]);
            A1[T][0] = MFMA(w, bl[0], A1[T][0]);
            A1[T][1] = MFMA(w, bh[1], A1[T][1]);
            A1[T][1] = MFMA(w, bl[1], A1[T][1]);
        }
    }
    #pragma unroll
    for (int T = 0; T < 8; ++T) { A1[T][0] = lrelu4(A1[T][0]); A1[T][1] = lrelu4(A1[T][1]); }

    f32x4 A2[4][2];
    #pragma unroll
    for (int T = 0; T < 4; ++T) {
        f32x4 ci = ld_bias4(bf2 + T * 16 + 4 * g);
        A2[T][0] = ci; A2[T][1] = ci;
    }
    #pragma unroll
    for (int s = 0; s < 4; ++s) {
        bf16x8 bh[2], bl[2];
        #pragma unroll
        for (int u = 0; u < 2; ++u) {
            float vv[8] = {A1[2*s][u][0], A1[2*s][u][1], A1[2*s][u][2], A1[2*s][u][3],
                           A1[2*s+1][u][0], A1[2*s+1][u][1], A1[2*s+1][u][2], A1[2*s+1][u][3]};
            splitpack(vv, bh[u], bl[u]);
        }
        #pragma unroll
        for (int T = 0; T < 4; ++T) {
            bf16x8 w = ld_wf(WF + W2B + (T * 4 + s) * 64 + lane);
            A2[T][0] = MFMA(w, bh[0], A2[T][0]);
            A2[T][0] = MFMA(w, bl[0], A2[T][0]);
            A2[T][1] = MFMA(w, bh[1], A2[T][1]);
            A2[T][1] = MFMA(w, bl[1], A2[T][1]);
        }
    }
    #pragma unroll
    for (int T = 0; T < 4; ++T) { A2[T][0] = lrelu4(A2[T][0]); A2[T][1] = lrelu4(A2[T][1]); }

    f32x4 A3[2][2];
    #pragma unroll
    for (int T = 0; T < 2; ++T) {
        f32x4 ci = ld_bias4(bf3 + T * 16 + 4 * g);
        A3[T][0] = ci; A3[T][1] = ci;
    }
    #pragma unroll
    for (int s = 0; s < 2; ++s) {
        bf16x8 bh[2], bl[2];
        #pragma unroll
        for (int u = 0; u < 2; ++u) {
            float vv[8] = {A2[2*s][u][0], A2[2*s][u][1], A2[2*s][u][2], A2[2*s][u][3],
                           A2[2*s+1][u][0], A2[2*s+1][u][1], A2[2*s+1][u][2], A2[2*s+1][u][3]};
            splitpack(vv, bh[u], bl[u]);
        }
        #pragma unroll
        for (int T = 0; T < 2; ++T) {
            bf16x8 w = ld_wf(WF + W3B + (T * 2 + s) * 64 + lane);
            A3[T][0] = MFMA(w, bh[0], A3[T][0]);
            A3[T][0] = MFMA(w, bl[0], A3[T][0]);
            A3[T][1] = MFMA(w, bh[1], A3[T][1]);
            A3[T][1] = MFMA(w, bl[1], A3[T][1]);
        }
    }
    #pragma unroll
    for (int T = 0; T < 2; ++T) { A3[T][0] = lrelu4(A3[T][0]); A3[T][1] = lrelu4(A3[T][1]); }

    float4 woa = *(const float4*)&Wo[4 * g];
    float4 wob = *(const float4*)&Wo[16 + 4 * g];
    float z0 = A3[0][0][0]*woa.x + A3[0][0][1]*woa.y + A3[0][0][2]*woa.z + A3[0][0][3]*woa.w
             + A3[1][0][0]*wob.x + A3[1][0][1]*wob.y + A3[1][0][2]*wob.z + A3[1][0][3]*wob.w;
    float z1 = A3[0][1][0]*woa.x + A3[0][1][1]*woa.y + A3[0][1][2]*woa.z + A3[0][1][3]*woa.w
             + A3[1][1][0]*wob.x + A3[1][1][1]*wob.y + A3[1][1][2]*wob.z + A3[1][1][3]*wob.w;
    z0 += __shfl_xor(z0, 16); z0 += __shfl_xor(z0, 32);
    z1 += __shfl_xor(z1, 16); z1 += __shfl_xor(z1, 32);
    float bb = bo[0];
    if (g == 0 && n0 < NN) out[n0] = 1.f / (1.f + __expf(-(z0 + bb)));
    if (g == 1 && n1 < NN) out[n1] = 1.f / (1.f + __expf(-(z1 + bb)));
}

extern "C" void kernel_launch(void* const* d_in, const int* in_sizes, int n_in,
                              void* d_out, int out_size, void* d_ws, size_t ws_size,
                              hipStream_t stream)
{
    (void)in_sizes; (void)n_in; (void)out_size; (void)d_ws; (void)ws_size;
    float* out = (float*)d_out;

    const float* x   = (const float*)d_in[0];
    const int*  col  = (const int*) d_in[1];
    const float* Wi0 = (const float*)d_in[2];
    const float* bi0 = (const float*)d_in[3];
    const float* gi0 = (const float*)d_in[4];
    const float* bei0= (const float*)d_in[5];
    const float* Wi1 = (const float*)d_in[6];
    const float* bi1 = (const float*)d_in[7];
    const float* gi1 = (const float*)d_in[8];
    const float* bei1= (const float*)d_in[9];
    const float* Wm  = (const float*)d_in[10];
    const float* bm  = (const float*)d_in[11];
    const float* gm  = (const float*)d_in[12];
    const float* bem = (const float*)d_in[13];
    const float* Wu  = (const float*)d_in[14];
    const float* bu  = (const float*)d_in[15];
    const float* gu  = (const float*)d_in[16];
    const float* beu = (const float*)d_in[17];
    const float* Wf0 = (const float*)d_in[18];
    const float* bf0 = (const float*)d_in[19];
    const float* Wf1 = (const float*)d_in[20];
    const float* bf1 = (const float*)d_in[21];
    const float* Wf2 = (const float*)d_in[22];
    const float* bf2 = (const float*)d_in[23];
    const float* Wf3 = (const float*)d_in[24];
    const float* bf3 = (const float*)d_in[25];
    const float* Wo  = (const float*)d_in[26];
    const float* bo  = (const float*)d_in[27];

    const int st_i0 = OFF_STATS;
    const int st_i1 = OFF_STATS + ST_STRIDE;
    const int st_m  = OFF_STATS + 2 * ST_STRIDE;    // + i*ST_STRIDE
    const int st_u  = OFF_STATS + 12 * ST_STRIDE;   // + i*ST_STRIDE

    const int RING[4] = { OFF_RING, OFF_RING + NV, OFF_RING + 2 * NV, OFF_RING + 3 * NV };

    dim3 blk(256);
    k_zero_v19<<<NBLK, blk, 0, stream>>>();
    k_bcnt_v19<<<NCBLK, blk, 0, stream>>>(col);
    k_bscan_v19<<<1, 512, 0, stream>>>();
    k_binfill_v19<<<NCBLK, blk, 0, stream>>>(col);
    k_csr_v27<<<NBKT, blk, 0, stream>>>();
    k_wprep_v18<<<200, blk, 0, stream>>>(Wf0, Wf1, Wf2, Wf3);

    // init MLP: x -> h0 (ring[0]); last k_nl chains layer-0 msg linear into bf16 MSGB
    k_init0_v17<<<1024, blk, 0, stream>>>(x, Wi0, bi0);
    k_nl_v29<<<6250, dim3(64), 0, stream>>>(OFF_PA, OFF_PB, 0, st_i0, gi0, bei0, -1, -1, Wi1, bi1, st_i1);
    k_nl_v29<<<6250, dim3(64), 0, stream>>>(OFF_PB, 0, 1, st_i1, gi1, bei1, -1, RING[0], Wm, bm, st_m);

    for (int i = 0; i < 10; ++i) {
        int h_cur = RING[i & 3];
        int h_new = RING[(i + 1) & 3];
        int resid = (i >= 2) ? RING[(i - 2) & 3] : -1;
        k_act_v21<<<1563, blk, 0, stream>>>(st_m + i * ST_STRIDE, gm + i * 32, bem + i * 32);
        k_gupd_v28<<<NGBLK, dim3(64), 0, stream>>>(h_cur, Wu + i * 2048, bu + i * 32,
                                                   st_u + i * ST_STRIDE);
        const float* Wn = (i < 9) ? (Wm + (i + 1) * 1024) : nullptr;
        const float* bn = (i < 9) ? (bm + (i + 1) * 32) : nullptr;
        int st_next = (i < 9) ? (st_m + (i + 1) * ST_STRIDE) : 0;
        k_nl_v29<<<6250, dim3(64), 0, stream>>>(OFF_PB, 0, 1, st_u + i * ST_STRIDE,
                                                gu + i * 32, beu + i * 32,
                                                resid, h_new, Wn, bn, st_next);
    }

    k_final_v18<<<782, blk, 0, stream>>>(RING[2], bf0, bf1, bf2, bf3, Wo, bo, out);
}